// Round 11
// baseline (631.756 us; speedup 1.0000x reference)
//
#include <hip/hip_runtime.h>
#include <hip/hip_fp16.h>

#define BB 1024
#define SS 128
#define FF 64
#define HH 100

typedef _Float16 h8 __attribute__((ext_vector_type(8)));
typedef _Float16 h4 __attribute__((ext_vector_type(4)));
typedef float f4v __attribute__((ext_vector_type(4)));

// --- fast transcendentals ---------------------------------------------------
// v_rcp_f32 (~1 ulp); fp32 '/' without fast-math is ~11 VALU ops (R5: -32%).
// exp2-domain gates (R6): fold 1/ln2 (and tanh's 2x) into weights/biases.
// R7: product fusion sigma(zi)*tanh(zt) = (Et-1)*rcp((1+Ei)(1+Et)).
// R10: cell state kept pre-scaled (cst2 = c*2/ln2).
#define S_SIG  (-1.4426950408889634f)   // i,f,o rows: acc = -z/ln2
#define S_TANH ( 2.8853900817779268f)   // g rows:     acc = 2z/ln2
#define LOG2E  ( 1.4426950408889634f)
__device__ __forceinline__ float frcp(float x){ return __builtin_amdgcn_rcpf(x); }
__device__ __forceinline__ float fexp2(float x){ return __builtin_amdgcn_exp2f(x); }
__device__ __forceinline__ float sigm2(float a){ return frcp(1.f + fexp2(a)); }        // a = -z/ln2
__device__ __forceinline__ float tanh2(float a){ return 1.f - 2.f*frcp(fexp2(a)+1.f);} // a = 2z/ln2
__device__ __forceinline__ float ftanh(float x){ return tanh2(x*S_TANH); }             // unscaled arg
__device__ __forceinline__ float sigtanh(float Ei, float Et){
  float D = __builtin_fmaf(Ei, Et, Ei) + (Et + 1.f);   // (1+Ei)(1+Et)
  return (Et - 1.f) * frcp(D);
}
// S_TANH * sigma * tanh (for the pre-scaled cell state):
__device__ __forceinline__ float sigtanhT(float Ei, float Et){
  float D = __builtin_fmaf(Ei, Et, Ei) + (Et + 1.f);
  return __builtin_fmaf(S_TANH, Et, -S_TANH) * frcp(D);
}

// LDS-only barrier: waits own LDS ops, does NOT drain vmcnt (global stores
// stay in flight across steps).
#define LDS_BARRIER() __asm__ __volatile__("s_waitcnt lgkmcnt(0)\ns_barrier" ::: "memory")

__device__ __forceinline__ float wsum(float v){
#pragma unroll
  for (int m = 32; m >= 1; m >>= 1) v += __shfl_xor(v, m, 64);
  return v;
}
__device__ __forceinline__ float wmax(float v){
#pragma unroll
  for (int m = 32; m >= 1; m >>= 1) v = fmaxf(v, __shfl_xor(v, m, 64));
  return v;
}

// ====== gram + conv1pool + conv2 + mean FUSED (one block per batch) ======
__global__ __launch_bounds__(512) void k_conv(const float* __restrict__ x,
    const float* __restrict__ c1w, const float* __restrict__ c1b,
    const float* __restrict__ c2w, const float* __restrict__ c2b,
    float* __restrict__ proc){
  __shared__ __align__(16) char smem[64256];
  _Float16* img2 = (_Float16*)smem;              // 8712 B
  float*    xs   = (float*)(smem + 8720);        // 32768 B (dies at img zero)
  _Float16* img  = (_Float16*)(smem + 8720);     // 55536 B
  float*    red  = (float*)smem;                 // 1024 B (alias img2, late)
  int tid = threadIdx.x, b = blockIdx.x;
  int wv = tid>>6, l = tid&63, lm = l&15, lq = l>>4;
  h8 bfr[2][5];
  float biasv[2];
#pragma unroll
  for (int nt=0; nt<2; ++nt){
    int oc = nt*16 + lm;
    biasv[nt] = c2b[oc];
#pragma unroll
    for (int c=0;c<5;++c){
      h8 f;
#pragma unroll
      for (int j=0;j<8;++j){
        int k = c*32 + lq*8 + j;
        int tap = k>>4, ic = k&15;
        f[j] = (_Float16)((tap<9) ? c2w[oc*144 + ic*9 + tap] : 0.f);
      }
      bfr[nt][c]=f;
    }
  }
  {
    const float* xb = x + (size_t)b*SS*FF;
    for (int i = tid; i < SS*FF/4; i += 512)
      ((float4*)xs)[i] = ((const float4*)xb)[i];
    for (int i = tid; i < 66*66; i += 512) img2[i] = (_Float16)0.f;
  }
  __syncthreads();
  {
    int ti = (tid & 31)*2, tj = (tid >> 5)*4;
    float acc[2][4];
#pragma unroll
    for (int a=0;a<2;++a)
#pragma unroll
      for (int c=0;c<4;++c) acc[a][c]=0.f;
    for (int s = 0; s < SS; ++s){
      const float* row = xs + s*FF;
      float a0 = row[ti], a1 = row[ti+1];
      float4 bv = *(const float4*)(row + tj);
      float bb2[4] = {bv.x,bv.y,bv.z,bv.w};
#pragma unroll
      for (int c=0;c<4;++c){ acc[0][c] += a0*bb2[c]; acc[1][c] += a1*bb2[c]; }
    }
    __syncthreads();
#pragma unroll
    for (int a=0;a<2;++a)
#pragma unroll
      for (int c=0;c<4;++c) img2[(ti+a+1)*66 + (tj+c+1)] = (_Float16)acc[a][c];
  }
  {
    h8 z = {0,0,0,0,0,0,0,0};
    for (int i=tid; i<(34*34+1)*3; i+=512) ((h8*)img)[i] = z;
  }
  __syncthreads();
  {
    int oc = tid>>5, slot = tid&31;
    float wr[9];
#pragma unroll
    for (int t=0;t<9;++t) wr[t]=c1w[oc*9+t];
    float bo = c1b[oc];
    for (int p=slot;p<1024;p+=32){
      int py=p>>5, px=p&31;
      int y0=py*2, x0=px*2;
      float v[4][4];
#pragma unroll
      for (int wy=0;wy<4;++wy)
#pragma unroll
        for (int wxx=0;wxx<4;++wxx) v[wy][wxx]=(float)img2[(y0+wy)*66 + x0+wxx];
      float s00=bo,s01=bo,s10=bo,s11=bo;
#pragma unroll
      for (int ky=0;ky<3;++ky)
#pragma unroll
        for (int kx=0;kx<3;++kx){
          float w=wr[ky*3+kx];
          s00 += v[ky][kx]*w;   s01 += v[ky][kx+1]*w;
          s10 += v[ky+1][kx]*w; s11 += v[ky+1][kx+1]*w;
        }
      float mx = fmaxf(fmaxf(s00,s01),fmaxf(s10,s11));
      img[((py+1)*34 + (px+1))*24 + oc] = (_Float16)fmaxf(mx,0.f);
    }
  }
  __syncthreads();
  f4v ssum0 = {0,0,0,0}, ssum1 = {0,0,0,0};
#pragma unroll 2
  for (int i=0;i<8;++i){
    int mt = wv + i*8;
    int y = mt>>1, x0 = (mt&1)*16;
    h8 afr[5];
#pragma unroll
    for (int c=0;c<5;++c){
      int tap = 2*c + (lq>>1);
      int addr;
      if (c==4 && lq>=2) addr = 34*34*24;
      else {
        int dy = tap/3 - 1, dx = tap - (tap/3)*3 - 1;
        addr = ((y+dy+1)*34 + (x0+lm+dx+1))*24 + (lq&1)*8;
      }
      afr[c] = *(const h8*)&img[addr];
    }
    f4v a0 = {biasv[0],biasv[0],biasv[0],biasv[0]};
    f4v a1 = {biasv[1],biasv[1],biasv[1],biasv[1]};
#pragma unroll
    for (int c=0;c<5;++c){
      a0 = __builtin_amdgcn_mfma_f32_16x16x32_f16(afr[c], bfr[0][c], a0, 0,0,0);
      a1 = __builtin_amdgcn_mfma_f32_16x16x32_f16(afr[c], bfr[1][c], a1, 0,0,0);
    }
#pragma unroll
    for (int r=0;r<4;++r){
      ssum0[r] += fmaxf(a0[r],0.f);
      ssum1[r] += fmaxf(a1[r],0.f);
    }
  }
  float s0 = ssum0[0]+ssum0[1]+ssum0[2]+ssum0[3];
  float s1 = ssum1[0]+ssum1[1]+ssum1[2]+ssum1[3];
  s0 += __shfl_xor(s0,16,64); s0 += __shfl_xor(s0,32,64);
  s1 += __shfl_xor(s1,16,64); s1 += __shfl_xor(s1,32,64);
  __syncthreads();
  if (lq==0){ red[wv*32+lm]=s0; red[wv*32+16+lm]=s1; }
  __syncthreads();
  if (tid<32){
    float t=0.f;
#pragma unroll
    for (int w2=0;w2<8;++w2) t += red[w2*32+tid];
    proc[b*32+tid] = t*(1.f/1024.f);
  }
}

// ====== R11: fused feature pipeline, de-spilled ======
// R10 counters: k_feat was the top kernel (161us) with VGPR=128 and WRITE
// 86MB vs 50MB ideal -- the g2 group loop kept all 4 layers' weight frags
// (~112 VGPR) + biases live across iterations -> ~180-reg demand -> spill
// stores (+36MB; reloads L2-hot so FETCH unchanged). Fix: ONE group per wave
// (grid 1024->2048, no loop) + each layer's weights loaded right before use,
// so lifetimes end at the layer and peak live regs ~100.
#define TADDR(row,k) (((row)<<7) + (((((k)>>3) ^ (row)) & 15)<<3) + ((k)&7))
__global__ __launch_bounds__(256) void k_feat(const float* __restrict__ x,
    const float* __restrict__ proc,
    const float* __restrict__ fW1, const float* __restrict__ fb1,
    const float* __restrict__ fW2, const float* __restrict__ fb2,
    const float* __restrict__ cW1, const float* __restrict__ cb1,
    const float* __restrict__ cW2, const float* __restrict__ cb2,
    float* __restrict__ fw_out, _Float16* __restrict__ wxh){
  __shared__ __align__(16) _Float16 tiles[4][3][2048];   // [wave][xt,tA,tB][16*128]
  __shared__ __align__(16) _Float16 proc_h[32];
  int tid = threadIdx.x, w = tid>>6, l = tid&63, lm = l&15, lq = l>>4;
  int b = blockIdx.x >> 1;                 // 2 blocks per batch
  size_t R0 = ((size_t)blockIdx.x*4 + w) * 16;   // global 16-row group
  if (tid<32) proc_h[tid] = (_Float16)proc[b*32+tid];
  _Float16* xt = tiles[w][0];
  _Float16* tA = tiles[w][1];
  _Float16* tB = tiles[w][2];
  // stage x rows (f16): lane covers row lm, feats lq*16..+15
  {
    const float* xr = x + (R0+lm)*64 + lq*16;
    float4 x0 = *(const float4*)xr;
    float4 x1 = *(const float4*)(xr+4);
    float4 x2 = *(const float4*)(xr+8);
    float4 x3 = *(const float4*)(xr+12);
    h8 hx0 = {(_Float16)x0.x,(_Float16)x0.y,(_Float16)x0.z,(_Float16)x0.w,
              (_Float16)x1.x,(_Float16)x1.y,(_Float16)x1.z,(_Float16)x1.w};
    h8 hx1 = {(_Float16)x2.x,(_Float16)x2.y,(_Float16)x2.z,(_Float16)x2.w,
              (_Float16)x3.x,(_Float16)x3.y,(_Float16)x3.z,(_Float16)x3.w};
    *(h8*)&xt[TADDR(lm, lq*16)] = hx0;
    *(h8*)&xt[TADDR(lm, lq*16+8)] = hx1;
  }
  __syncthreads();
  // proc part of cmb (k=64..95)
  {
    h8 ph = *(const h8*)&proc_h[lq*8];
    *(h8*)&tB[TADDR(lm, 64+lq*8)] = ph;
  }
  // ---- L1: t1[32,16] = tanh2(W1s @ x + b1s) ----
  {
    h8 wfr1[2][2];
#pragma unroll
    for (int mt=0; mt<2; ++mt)
#pragma unroll
      for (int kc=0; kc<2; ++kc){
        h8 f;
#pragma unroll
        for (int j=0;j<8;++j) f[j] = (_Float16)(fW1[(mt*16+lm)*64 + kc*32 + lq*8 + j]*S_TANH);
        wfr1[mt][kc]=f;
      }
    h8 bx0 = *(const h8*)&xt[TADDR(lm, lq*8)];
    h8 bx1 = *(const h8*)&xt[TADDR(lm, 32+lq*8)];
#pragma unroll
    for (int mt=0;mt<2;++mt){
      float4 t = *(const float4*)&fb1[mt*16 + lq*4];
      f4v bv = {t.x*S_TANH, t.y*S_TANH, t.z*S_TANH, t.w*S_TANH};
      f4v a = __builtin_amdgcn_mfma_f32_16x16x32_f16(wfr1[mt][0], bx0, bv,0,0,0);
      a = __builtin_amdgcn_mfma_f32_16x16x32_f16(wfr1[mt][1], bx1, a,0,0,0);
      h4 tv = {(_Float16)tanh2(a[0]),(_Float16)tanh2(a[1]),
               (_Float16)tanh2(a[2]),(_Float16)tanh2(a[3])};
      *(h4*)&tA[TADDR(lm, mt*16+lq*4)] = tv;
    }
  }
  __syncthreads();
  // ---- L2: fs[64,16] = W2 @ t1 + b2 -> cmb k=0..63 ----
  {
    h8 bt = *(const h8*)&tA[TADDR(lm, lq*8)];
#pragma unroll
    for (int mt=0;mt<4;++mt){
      h8 f;
#pragma unroll
      for (int j=0;j<8;++j) f[j] = (_Float16)(fW2[(mt*16+lm)*32 + lq*8 + j]);
      float4 t = *(const float4*)&fb2[mt*16 + lq*4];
      f4v bv = {t.x, t.y, t.z, t.w};
      f4v a = __builtin_amdgcn_mfma_f32_16x16x32_f16(f, bt, bv,0,0,0);
      h4 fv = {(_Float16)a[0],(_Float16)a[1],(_Float16)a[2],(_Float16)a[3]};
      *(h4*)&tB[TADDR(lm, mt*16+lq*4)] = fv;
    }
  }
  __syncthreads();
  // ---- L3: h2[64,16] = tanh2(cW1s @ cmb + b3s) ----
  {
    h8 wfr3[4][3];
#pragma unroll
    for (int mt=0; mt<4; ++mt)
#pragma unroll
      for (int kc=0; kc<3; ++kc){
        h8 f;
#pragma unroll
        for (int j=0;j<8;++j) f[j] = (_Float16)(cW1[(mt*16+lm)*96 + kc*32 + lq*8 + j]*S_TANH);
        wfr3[mt][kc]=f;
      }
    h8 bc0 = *(const h8*)&tB[TADDR(lm, lq*8)];
    h8 bc1 = *(const h8*)&tB[TADDR(lm, 32+lq*8)];
    h8 bc2 = *(const h8*)&tB[TADDR(lm, 64+lq*8)];
#pragma unroll
    for (int mt=0;mt<4;++mt){
      float4 t = *(const float4*)&cb1[mt*16 + lq*4];
      f4v bv = {t.x*S_TANH, t.y*S_TANH, t.z*S_TANH, t.w*S_TANH};
      f4v z = {0.f,0.f,0.f,0.f};
      f4v a = __builtin_amdgcn_mfma_f32_16x16x32_f16(wfr3[mt][0], bc0, bv,0,0,0);
      f4v c = __builtin_amdgcn_mfma_f32_16x16x32_f16(wfr3[mt][1], bc1, z,0,0,0);
      a = __builtin_amdgcn_mfma_f32_16x16x32_f16(wfr3[mt][2], bc2, a,0,0,0);
      a = a + c;
      h4 hv = {(_Float16)tanh2(a[0]),(_Float16)tanh2(a[1]),
               (_Float16)tanh2(a[2]),(_Float16)tanh2(a[3])};
      *(h4*)&tA[TADDR(lm, mt*16+lq*4)] = hv;
    }
  }
  __syncthreads();
  // ---- L4: aw[64,16] = cW2 @ h2 + b4; softmax_m; outputs ----
  f4v a4[4];
  {
    h8 bh0 = *(const h8*)&tA[TADDR(lm, lq*8)];
    h8 bh1 = *(const h8*)&tA[TADDR(lm, 32+lq*8)];
#pragma unroll
    for (int mt=0;mt<4;++mt){
      h8 f0, f1;
#pragma unroll
      for (int j=0;j<8;++j){
        f0[j] = (_Float16)(cW2[(mt*16+lm)*64 + lq*8 + j]);
        f1[j] = (_Float16)(cW2[(mt*16+lm)*64 + 32 + lq*8 + j]);
      }
      float4 t = *(const float4*)&cb2[mt*16 + lq*4];
      f4v bv = {t.x, t.y, t.z, t.w};
      f4v a = __builtin_amdgcn_mfma_f32_16x16x32_f16(f0, bh0, bv,0,0,0);
      a4[mt] = __builtin_amdgcn_mfma_f32_16x16x32_f16(f1, bh1, a,0,0,0);
    }
  }
  float mx = a4[0][0];
#pragma unroll
  for (int mt=0;mt<4;++mt)
#pragma unroll
    for (int r=0;r<4;++r) mx = fmaxf(mx, a4[mt][r]);
  mx = fmaxf(mx, __shfl_xor(mx,16,64));
  mx = fmaxf(mx, __shfl_xor(mx,32,64));
  f4v e4[4];
  float s = 0.f;
#pragma unroll
  for (int mt=0;mt<4;++mt)
#pragma unroll
    for (int r=0;r<4;++r){
      float e = fexp2((a4[mt][r]-mx)*LOG2E);
      e4[mt][r] = e; s += e;
    }
  s += __shfl_xor(s,16,64);
  s += __shfl_xor(s,32,64);
  float rs = frcp(s);
#pragma unroll
  for (int mt=0;mt<4;++mt){
    h4 xh = *(const h4*)&xt[TADDR(lm, mt*16+lq*4)];
    float4 fwv;
    fwv.x = e4[mt][0]*rs; fwv.y = e4[mt][1]*rs;
    fwv.z = e4[mt][2]*rs; fwv.w = e4[mt][3]*rs;
    h4 wh = {(_Float16)((float)xh[0]*fwv.x), (_Float16)((float)xh[1]*fwv.y),
             (_Float16)((float)xh[2]*fwv.z), (_Float16)((float)xh[3]*fwv.w)};
    size_t off = (R0+lm)*64 + mt*16 + lq*4;
    *(float4*)&fw_out[off] = fwv;
    *(h4*)&wxh[off] = wh;
  }
}

// ================= MFMA encoder LSTM (swapped operands) =================
// ench: f16 copy of enc, row-padded to 112 (units 100..111 zeroed).
__global__ __launch_bounds__(448) void k_enc_mfma(const _Float16* __restrict__ wxh,
    const float* __restrict__ Wih, const float* __restrict__ Whh,
    const float* __restrict__ bih, const float* __restrict__ bhh,
    _Float16* __restrict__ ench){
  __shared__ __align__(16) _Float16 hbuf[2][16*128];
  __shared__ __align__(16) _Float16 xst[2][16*64];
  int tid = threadIdx.x;
  int w = tid >> 6, l = tid & 63;
  int lm = l & 15, lq = l >> 4;
  int b0 = blockIdx.x * 16;
  int au = w*16 + lm;
  bool avalid = au < 100;
  int u0 = w*16 + lq*4;
  bool uvalid = (u0 + 3) < 100;
  const float gsc[4] = {S_SIG, S_SIG, S_TANH, S_SIG};   // gate order i,f,g,o
  h8 wfr[4][6];
#pragma unroll
  for (int tt=0; tt<4; ++tt){
    int row = tt*100 + au;
#pragma unroll
    for (int cc=0; cc<6; ++cc){
      h8 f;
#pragma unroll
      for (int j=0;j<8;++j){
        int kg = cc*32 + lq*8 + j;
        float v = 0.f;
        if (avalid){
          if (kg < 64) v = Wih[(size_t)row*64 + kg];
          else { int kh = kg - 64; if (kh < 100) v = Whh[(size_t)row*100 + kh]; }
        }
        f[j] = (_Float16)(v*gsc[tt]);
      }
      wfr[tt][cc] = f;
    }
  }
  f4v biasv[4];
#pragma unroll
  for (int tt=0; tt<4; ++tt){
    if (uvalid){
      float4 bi = *(const float4*)&bih[tt*100 + u0];
      float4 bh = *(const float4*)&bhh[tt*100 + u0];
      float s = gsc[tt];
      f4v bv2 = {(bi.x+bh.x)*s, (bi.y+bh.y)*s, (bi.z+bh.z)*s, (bi.w+bh.w)*s};
      biasv[tt] = bv2;
    } else { f4v z = {0,0,0,0}; biasv[tt] = z; }
  }
  for (int i = tid; i < 2*16*128; i += 448) hbuf[0][i] = (_Float16)0.f;
  int sm = tid >> 4, skq = tid & 15;
  bool doPref = (tid < 256);
  int xwaddr = sm*64 + (((skq>>1) ^ (sm&7))<<3) + (skq&1)*4;
  h4 rA, rB;
  if (doPref){
    *(h4*)&xst[0][xwaddr] = *(const h4*)(wxh + ((size_t)(b0+sm)*SS + 0)*FF + skq*4);
    rA = *(const h4*)(wxh + ((size_t)(b0+sm)*SS + 1)*FF + skq*4);   // x(1)
  }
  float cst[4] = {0.f,0.f,0.f,0.f};   // pre-scaled cell state (c * 2/ln2)
  int hwaddr = lm*128 + (((2*w + (lq>>1)) ^ (lm&7))<<3) + (lq&1)*4;
  __syncthreads();

#define ENC_STEP(T, CUR, RCONS, RISSUE)                                          \
  {                                                                              \
    const int cur = (CUR), nxt = (CUR)^1;                                        \
    if (doPref && (T) < SS-2)                                                    \
      RISSUE = *(const h4*)(wxh + ((size_t)(b0+sm)*SS + ((T)+2))*FF + skq*4);    \
    h8 bact[6];                                                                  \
    _Pragma("unroll")                                                            \
    for (int cc=0; cc<2; ++cc)                                                   \
      bact[cc] = *(const h8*)&xst[cur][lm*64 + (((cc*4+lq) ^ (lm&7))<<3)];       \
    _Pragma("unroll")                                                            \
    for (int cc=0; cc<4; ++cc)                                                   \
      bact[2+cc] = *(const h8*)&hbuf[cur][lm*128 + (((cc*4+lq) ^ (lm&7))<<3)];   \
    f4v acc[4];                                                                  \
    __builtin_amdgcn_s_setprio(1);                                               \
    _Pragma("unroll")                                                            \
    for (int tt=0; tt<4; ++tt){                                                  \
      f4v a1 = biasv[tt];                                                        \
      f4v a2 = {0.f,0.f,0.f,0.f};                                                \
      a1 = __builtin_amdgcn_mfma_f32_16x16x32_f16(wfr[tt][0], bact[0], a1, 0,0,0); \
      a2 = __builtin_amdgcn_mfma_f32_16x16x32_f16(wfr[tt][1], bact[1], a2, 0,0,0); \
      a1 = __builtin_amdgcn_mfma_f32_16x16x32_f16(wfr[tt][2], bact[2], a1, 0,0,0); \
      a2 = __builtin_amdgcn_mfma_f32_16x16x32_f16(wfr[tt][3], bact[3], a2, 0,0,0); \
      a1 = __builtin_amdgcn_mfma_f32_16x16x32_f16(wfr[tt][4], bact[4], a1, 0,0,0); \
      a2 = __builtin_amdgcn_mfma_f32_16x16x32_f16(wfr[tt][5], bact[5], a2, 0,0,0); \
      acc[tt] = a1 + a2;                                                         \
    }                                                                            \
    __builtin_amdgcn_s_setprio(0);                                               \
    float hn[4];                                                                 \
    _Pragma("unroll")                                                            \
    for (int r=0;r<4;++r){                                                       \
      float Ei = fexp2(acc[0][r]), Ef = fexp2(acc[1][r]);                        \
      float Eg = fexp2(acc[2][r]), Eo = fexp2(acc[3][r]);                        \
      float cn2 = frcp(1.f+Ef)*cst[r] + sigtanhT(Ei, Eg);                        \
      float Ec = fexp2(cn2);                                                     \
      hn[r] = sigtanh(Eo, Ec);                                                   \
      cst[r] = cn2;                                                              \
    }                                                                            \
    if (uvalid){                                                                 \
      h4 hp = {(_Float16)hn[0],(_Float16)hn[1],(_Float16)hn[2],(_Float16)hn[3]}; \
      *(h4*)&hbuf[nxt][hwaddr] = hp;                                             \
      *(h4*)&ench[((size_t)(b0+lm)*SS + (T))*112 + u0] = hp;                     \
    } else {                                                                     \
      h4 z = {(_Float16)0.f,(_Float16)0.f,(_Float16)0.f,(_Float16)0.f};          \
      *(h4*)&ench[((size_t)(b0+lm)*SS + (T))*112 + u0] = z;                      \
    }                                                                            \
    if (doPref && (T) < SS-1){                                                   \
      *(h4*)&xst[nxt][xwaddr] = RCONS;                                           \
    }                                                                            \
    LDS_BARRIER();                                                               \
  }

  for (int t = 0; t < SS; t += 2){
    ENC_STEP(t,   0, rA, rB)
    ENC_STEP(t+1, 1, rB, rA)
  }
#undef ENC_STEP
}

// ====== ts GEMM + attn2 FUSED (one block per batch) ======
__global__ __launch_bounds__(256) void k_tsattn2(const _Float16* __restrict__ ench,
    const float* __restrict__ aW1, const float* __restrict__ ab1,
    const float* __restrict__ aW2, const float* __restrict__ ab2,
    const float* __restrict__ bW, const float* __restrict__ bb_,
    const float* __restrict__ h0W, const float* __restrict__ h0b,
    const float* __restrict__ c0W, const float* __restrict__ c0b,
    const float* __restrict__ dWih, const float* __restrict__ dbih, const float* __restrict__ dbhh,
    float* __restrict__ tw_out, float* __restrict__ dh0, float* __restrict__ dc0,
    float* __restrict__ decpre){
  __shared__ float tsb[SS];
  __shared__ float ctxb[HH];
  __shared__ float ctx2[200];
  __shared__ float bottb[32];
  __shared__ float red[8];
  int tid = threadIdx.x, wv = tid>>6, lane = tid&63, lm = lane&15, lq = lane>>4;
  int b = blockIdx.x;
  {
    h8 bfr[4][4];
#pragma unroll
    for (int nt=0; nt<4; ++nt){
      int n = nt*16 + lm;
#pragma unroll
      for (int cc=0; cc<4; ++cc){
        h8 f;
#pragma unroll
        for (int j=0;j<8;++j){
          int k = cc*32 + lq*8 + j;
          f[j] = (_Float16)((k<100) ? aW1[n*100+k]*S_TANH : 0.f);
        }
        bfr[nt][cc]=f;
      }
    }
    float ab1v[4], aw2v[4];
#pragma unroll
    for (int nt=0; nt<4; ++nt){ ab1v[nt] = ab1[nt*16+lm]*S_TANH; aw2v[nt] = aW2[nt*16+lm]; }
    float ab2v = ab2[0];
#pragma unroll
    for (int i=0;i<2;++i){
      int M0 = b*SS + wv*32 + i*16;
      const _Float16* rowp = ench + (size_t)(M0+lm)*112;
      h8 afr[4];
#pragma unroll
      for (int cc=0; cc<3; ++cc)
        afr[cc] = *(const h8*)(rowp + cc*32 + lq*8);
      if (lq < 2) afr[3] = *(const h8*)(rowp + 96 + lq*8);
      else { h8 z={0,0,0,0,0,0,0,0}; afr[3]=z; }
      f4v acc[4];
#pragma unroll
      for (int nt=0; nt<4; ++nt){
        f4v a = {ab1v[nt],ab1v[nt],ab1v[nt],ab1v[nt]};
#pragma unroll
        for (int cc=0; cc<4; ++cc)
          a = __builtin_amdgcn_mfma_f32_16x16x32_f16(afr[cc], bfr[nt][cc], a, 0,0,0);
        acc[nt]=a;
      }
      float p[4];
#pragma unroll
      for (int r=0;r<4;++r){
        p[r] = aw2v[0]*tanh2(acc[0][r]) + aw2v[1]*tanh2(acc[1][r])
             + aw2v[2]*tanh2(acc[2][r]) + aw2v[3]*tanh2(acc[3][r]);
#pragma unroll
        for (int m=1;m<16;m<<=1) p[r] += __shfl_xor(p[r], m, 64);
      }
      if (lm==0){
        float4 st; st.x=p[0]+ab2v; st.y=p[1]+ab2v; st.z=p[2]+ab2v; st.w=p[3]+ab2v;
        *(float4*)&tsb[wv*32 + i*16 + lq*4] = st;
      }
    }
  }
  __syncthreads();
  const _Float16* encb = ench + (size_t)b*SS*112;
  float tv = (tid < SS) ? tsb[tid] : -1e30f;
  float m = wmax(tv);
  if (lane==0) red[wv]=m;
  __syncthreads();
  m = fmaxf(fmaxf(red[0],red[1]), fmaxf(red[2],red[3]));
  float e = (tid < SS) ? __expf(tv - m) : 0.f;
  float sm = wsum(e);
  if (lane==0) red[4+wv]=sm;
  __syncthreads();
  float denom = red[4]+red[5]+red[6]+red[7];
  float rden = frcp(denom);
  if (tid < SS){
    float twv = e*rden;
    tw_out[(size_t)b*SS + tid] = twv;
    tsb[tid] = twv;
  }
  __syncthreads();
  if (tid < 200){
    int u = (tid < 100) ? tid : (tid - 100);
    int sb = (tid < 100) ? 0 : 64;
    const _Float16* ep = encb + (size_t)sb*112 + u;
    const float* tp = tsb + sb;
    float a = 0.f;
#pragma unroll 4
    for (int s=0;s<64;++s) a += tp[s]*(float)ep[s*112];
    ctx2[tid] = a;
  }
  __syncthreads();
  if (tid < HH) ctxb[tid] = ctx2[tid] + ctx2[tid+100];
  __syncthreads();
  if (tid < 32){
    float a = bb_[tid];
    const float* wr = bW + tid*HH;
    for (int k=0;k<HH;++k) a += wr[k]*ctxb[k];
    bottb[tid]=a;
  }
  __syncthreads();
  if (tid < HH){
    float a = h0b[tid];
    const float* wr = h0W + tid*32;
#pragma unroll
    for (int k=0;k<32;++k) a += wr[k]*bottb[k];
    dh0[(size_t)b*HH + tid] = a;
  } else if (tid < 200){
    int jj = tid-100;
    float a = c0b[jj];
    const float* wr = c0W + jj*32;
#pragma unroll
    for (int k=0;k<32;++k) a += wr[k]*bottb[k];
    dc0[(size_t)b*HH + jj] = a;
  }
  {
    int jj = tid;
    float a = dbih[jj]+dbhh[jj];
    const float* wr = dWih + jj*32;
#pragma unroll
    for (int k=0;k<32;++k) a += wr[k]*bottb[k];
    decpre[(size_t)b*400 + jj] = a;
    jj = tid + 256;
    if (jj < 400){
      float a2v = dbih[jj]+dbhh[jj];
      const float* wr2 = dWih + jj*32;
#pragma unroll
      for (int k=0;k<32;++k) a2v += wr2[k]*bottb[k];
      decpre[(size_t)b*400 + jj] = a2v;
    }
  }
}

// ================= MFMA decoder LSTM (swapped operands) =================
// f16 dech output (112-pad zeroed for the MFMA k_out); pre-scaled cell state.
__global__ __launch_bounds__(448) void k_dec_mfma(const float* __restrict__ decpre,
    const float* __restrict__ Whh,
    const float* __restrict__ dh0, const float* __restrict__ dc0,
    _Float16* __restrict__ dech){
  __shared__ __align__(16) _Float16 hbuf[2][16*128];
  int tid = threadIdx.x;
  int w = tid >> 6, l = tid & 63;
  int lm = l & 15, lq = l >> 4;
  int b0 = blockIdx.x * 16;
  int au = w*16 + lm;
  bool avalid = au < 100;
  int u0 = w*16 + lq*4;
  bool uvalid = (u0 + 3) < 100;
  const float gsc[4] = {S_SIG, S_SIG, S_TANH, S_SIG};
  h8 wfr[4][4];
#pragma unroll
  for (int tt = 0; tt < 4; ++tt){
    int row = tt*100 + au;
#pragma unroll
    for (int cc = 0; cc < 4; ++cc){
      h8 f;
#pragma unroll
      for (int j = 0; j < 8; ++j){
        int kh = cc*32 + lq*8 + j;
        float v = (avalid && kh < 100) ? Whh[(size_t)row*100 + kh] : 0.f;
        f[j] = (_Float16)(v*gsc[tt]);
      }
      wfr[tt][cc] = f;
    }
  }
  f4v pre[4];
  float cst[4] = {0.f,0.f,0.f,0.f};
  if (uvalid){
#pragma unroll
    for (int tt = 0; tt < 4; ++tt){
      float4 p = *(const float4*)&decpre[(size_t)(b0+lm)*400 + tt*100 + u0];
      float s = gsc[tt];
      f4v pv = {p.x*s, p.y*s, p.z*s, p.w*s};
      pre[tt] = pv;
    }
    float4 c4 = *(const float4*)&dc0[(size_t)(b0+lm)*100 + u0];
    cst[0]=c4.x*S_TANH; cst[1]=c4.y*S_TANH; cst[2]=c4.z*S_TANH; cst[3]=c4.w*S_TANH;
  } else {
    f4v z = {0,0,0,0};
#pragma unroll
    for (int tt = 0; tt < 4; ++tt) pre[tt] = z;
  }
  for (int i = tid; i < 16*128; i += 448) hbuf[1][i] = (_Float16)0.f;
  for (int idx = tid; idx < 16*128; idx += 448){
    int m = idx >> 7, u2 = idx & 127;
    float v = (u2 < 100) ? dh0[(size_t)(b0+m)*HH + u2] : 0.f;
    hbuf[0][m*128 + (((u2>>3) ^ (m&7))<<3) + (u2&7)] = (_Float16)v;
  }
  int hwaddr = lm*128 + (((2*w + (lq>>1)) ^ (lm&7))<<3) + (lq&1)*4;
  __syncthreads();

#define DEC_STEP(T, CUR)                                                         \
  {                                                                              \
    const int cur = (CUR), nxt = (CUR)^1;                                        \
    h8 bact[4];                                                                  \
    _Pragma("unroll")                                                            \
    for (int cc = 0; cc < 4; ++cc)                                               \
      bact[cc] = *(const h8*)&hbuf[cur][lm*128 + (((cc*4+lq) ^ (lm&7))<<3)];     \
    f4v acc[4];                                                                  \
    __builtin_amdgcn_s_setprio(1);                                               \
    _Pragma("unroll")                                                            \
    for (int tt = 0; tt < 4; ++tt){                                              \
      f4v a1 = pre[tt];                                                          \
      f4v a2 = {0.f,0.f,0.f,0.f};                                                \
      a1 = __builtin_amdgcn_mfma_f32_16x16x32_f16(wfr[tt][0], bact[0], a1, 0,0,0); \
      a2 = __builtin_amdgcn_mfma_f32_16x16x32_f16(wfr[tt][1], bact[1], a2, 0,0,0); \
      a1 = __builtin_amdgcn_mfma_f32_16x16x32_f16(wfr[tt][2], bact[2], a1, 0,0,0); \
      a2 = __builtin_amdgcn_mfma_f32_16x16x32_f16(wfr[tt][3], bact[3], a2, 0,0,0); \
      acc[tt] = a1 + a2;                                                         \
    }                                                                            \
    __builtin_amdgcn_s_setprio(0);                                               \
    float hn[4];                                                                 \
    _Pragma("unroll")                                                            \
    for (int r=0;r<4;++r){                                                       \
      float Ei = fexp2(acc[0][r]), Ef = fexp2(acc[1][r]);                        \
      float Eg = fexp2(acc[2][r]), Eo = fexp2(acc[3][r]);                        \
      float cn2 = frcp(1.f+Ef)*cst[r] + sigtanhT(Ei, Eg);                        \
      float Ec = fexp2(cn2);                                                     \
      hn[r] = sigtanh(Eo, Ec);                                                   \
      cst[r] = cn2;                                                              \
    }                                                                            \
    if (uvalid){                                                                 \
      h4 hp = {(_Float16)hn[0],(_Float16)hn[1],(_Float16)hn[2],(_Float16)hn[3]}; \
      *(h4*)&hbuf[nxt][hwaddr] = hp;                                             \
      *(h4*)&dech[((size_t)(b0+lm)*SS + (T))*112 + u0] = hp;                     \
    } else {                                                                     \
      h4 z = {(_Float16)0.f,(_Float16)0.f,(_Float16)0.f,(_Float16)0.f};          \
      *(h4*)&dech[((size_t)(b0+lm)*SS + (T))*112 + u0] = z;                      \
    }                                                                            \
    LDS_BARRIER();                                                               \
  }

  for (int t = 0; t < SS; t += 2){
    DEC_STEP(t,   0)
    DEC_STEP(t+1, 1)
  }
#undef DEC_STEP
}

// ------------- out = dech @ oW^T + ob, MFMA -------------
__global__ __launch_bounds__(256) void k_out(const _Float16* __restrict__ dech,
    const float* __restrict__ oW, const float* __restrict__ ob, float* __restrict__ out0){
  int tid = threadIdx.x, wv = tid>>6, l = tid&63, lm = l&15, lq = l>>4;
  h8 bfr[4][4];
#pragma unroll
  for (int nt=0; nt<4; ++nt){
    int n = nt*16 + lm;
#pragma unroll
    for (int cc=0; cc<4; ++cc){
      h8 f;
#pragma unroll
      for (int j=0;j<8;++j){
        int k = cc*32 + lq*8 + j;
        f[j] = (_Float16)((k<100) ? oW[n*100+k] : 0.f);
      }
      bfr[nt][cc]=f;
    }
  }
  float obv[4];
#pragma unroll
  for (int nt=0; nt<4; ++nt) obv[nt] = ob[nt*16+lm];
  int tile0 = (blockIdx.x*4 + wv)*4;
#pragma unroll
  for (int i=0;i<4;++i){
    int M0 = (tile0+i)*16;
    const _Float16* rowp = dech + (size_t)(M0+lm)*112;
    h8 afr[4];
#pragma unroll
    for (int cc=0; cc<3; ++cc)
      afr[cc] = *(const h8*)(rowp + cc*32 + lq*8);
    if (lq < 2) afr[3] = *(const h8*)(rowp + 96 + lq*8);
    else { h8 z={0,0,0,0,0,0,0,0}; afr[3]=z; }
#pragma unroll
    for (int nt=0; nt<4; ++nt){
      f4v a = {obv[nt],obv[nt],obv[nt],obv[nt]};
#pragma unroll
      for (int cc=0; cc<4; ++cc)
        a = __builtin_amdgcn_mfma_f32_16x16x32_f16(afr[cc], bfr[nt][cc], a, 0,0,0);
#pragma unroll
      for (int r=0;r<4;++r)
        out0[(size_t)(M0 + lq*4 + r)*64 + nt*16 + lm] = a[r];
    }
  }
}

extern "C" void kernel_launch(void* const* d_in, const int* in_sizes, int n_in,
                              void* d_out, int out_size, void* d_ws, size_t ws_size,
                              hipStream_t stream) {
  const float* x    = (const float*)d_in[0];
  const float* c1w  = (const float*)d_in[1];
  const float* c1b  = (const float*)d_in[2];
  const float* c2w  = (const float*)d_in[3];
  const float* c2b  = (const float*)d_in[4];
  const float* fW1  = (const float*)d_in[5];
  const float* fb1  = (const float*)d_in[6];
  const float* fW2  = (const float*)d_in[7];
  const float* fb2  = (const float*)d_in[8];
  const float* cW1  = (const float*)d_in[9];
  const float* cb1  = (const float*)d_in[10];
  const float* cW2  = (const float*)d_in[11];
  const float* cb2  = (const float*)d_in[12];
  const float* eWih = (const float*)d_in[13];
  const float* eWhh = (const float*)d_in[14];
  const float* ebih = (const float*)d_in[15];
  const float* ebhh = (const float*)d_in[16];
  const float* aW1  = (const float*)d_in[17];
  const float* ab1  = (const float*)d_in[18];
  const float* aW2  = (const float*)d_in[19];
  const float* ab2  = (const float*)d_in[20];
  const float* bW   = (const float*)d_in[21];
  const float* bb   = (const float*)d_in[22];
  const float* h0W  = (const float*)d_in[23];
  const float* h0b  = (const float*)d_in[24];
  const float* c0W  = (const float*)d_in[25];
  const float* c0b  = (const float*)d_in[26];
  const float* dWih = (const float*)d_in[27];
  const float* dWhh = (const float*)d_in[28];
  const float* dbih = (const float*)d_in[29];
  const float* dbhh = (const float*)d_in[30];
  const float* oW   = (const float*)d_in[31];
  const float* ob   = (const float*)d_in[32];

  float* out0   = (float*)d_out;
  float* out_tw = out0 + (size_t)BB*SS*FF;
  float* out_fw = out_tw + (size_t)BB*SS;

  char* ws = (char*)d_ws;
  float*  proc   = (float*) (ws + 50331648);    // 0.13 MB
  _Float16* wxh  = (_Float16*)(ws + 84017152);  // 16.78 MB (f16, [b*S+s][64])
  float*  dh0    = (float*) (ws + 170000384);   // 0.41 MB
  float*  dc0    = (float*) (ws + 170409984);   // 0.41 MB
  float*  decpre = (float*) (ws + 170819584);   // 1.64 MB
  _Float16* dech = (_Float16*)(ws + 172457984); // 29.36 MB (f16, [row][112])
  _Float16* ench = (_Float16*)(ws + 50462720);  // 29.36 MB

  k_conv<<<BB, 512, 0, stream>>>(x, c1w, c1b, c2w, c2b, proc);
  k_feat<<<2048, 256, 0, stream>>>(x, proc, fW1, fb1, fW2, fb2,
                                   cW1, cb1, cW2, cb2, out_fw, wxh);
  k_enc_mfma<<<64, 448, 0, stream>>>(wxh, eWih, eWhh, ebih, ebhh, ench);
  k_tsattn2<<<BB, 256, 0, stream>>>(ench, aW1, ab1, aW2, ab2, bW, bb,
                                    h0W, h0b, c0W, c0b,
                                    dWih, dbih, dbhh, out_tw, dh0, dc0, decpre);
  k_dec_mfma<<<64, 448, 0, stream>>>(decpre, dWhh, dh0, dc0, dech);
  k_out<<<512, 256, 0, stream>>>(dech, oW, ob, out0);
}

// Round 12
// 595.710 us; speedup vs baseline: 1.0605x; 1.0605x over previous
//
#include <hip/hip_runtime.h>
#include <hip/hip_fp16.h>

#define BB 1024
#define SS 128
#define FF 64
#define HH 100

typedef _Float16 h8 __attribute__((ext_vector_type(8)));
typedef _Float16 h4 __attribute__((ext_vector_type(4)));
typedef float f4v __attribute__((ext_vector_type(4)));

// --- fast transcendentals ---------------------------------------------------
#define S_SIG  (-1.4426950408889634f)   // i,f,o rows: acc = -z/ln2
#define S_TANH ( 2.8853900817779268f)   // g rows:     acc = 2z/ln2
#define LOG2E  ( 1.4426950408889634f)
__device__ __forceinline__ float frcp(float x){ return __builtin_amdgcn_rcpf(x); }
__device__ __forceinline__ float fexp2(float x){ return __builtin_amdgcn_exp2f(x); }
__device__ __forceinline__ float sigm2(float a){ return frcp(1.f + fexp2(a)); }
__device__ __forceinline__ float tanh2(float a){ return 1.f - 2.f*frcp(fexp2(a)+1.f);}
__device__ __forceinline__ float ftanh(float x){ return tanh2(x*S_TANH); }
__device__ __forceinline__ float sigtanh(float Ei, float Et){
  float D = __builtin_fmaf(Ei, Et, Ei) + (Et + 1.f);
  return (Et - 1.f) * frcp(D);
}
__device__ __forceinline__ float sigtanhT(float Ei, float Et){
  float D = __builtin_fmaf(Ei, Et, Ei) + (Et + 1.f);
  return __builtin_fmaf(S_TANH, Et, -S_TANH) * frcp(D);
}

#define LDS_BARRIER() __asm__ __volatile__("s_waitcnt lgkmcnt(0)\ns_barrier" ::: "memory")

__device__ __forceinline__ float wsum(float v){
#pragma unroll
  for (int m = 32; m >= 1; m >>= 1) v += __shfl_xor(v, m, 64);
  return v;
}
__device__ __forceinline__ float wmax(float v){
#pragma unroll
  for (int m = 32; m >= 1; m >>= 1) v = fmaxf(v, __shfl_xor(v, m, 64));
  return v;
}

// ====== gram + conv1pool + conv2 + mean FUSED (one block per batch) ======
__global__ __launch_bounds__(512) void k_conv(const float* __restrict__ x,
    const float* __restrict__ c1w, const float* __restrict__ c1b,
    const float* __restrict__ c2w, const float* __restrict__ c2b,
    float* __restrict__ proc){
  __shared__ __align__(16) char smem[64256];
  _Float16* img2 = (_Float16*)smem;              // 8712 B
  float*    xs   = (float*)(smem + 8720);        // 32768 B (dies at img zero)
  _Float16* img  = (_Float16*)(smem + 8720);     // 55536 B
  float*    red  = (float*)smem;                 // 1024 B (alias img2, late)
  int tid = threadIdx.x, b = blockIdx.x;
  int wv = tid>>6, l = tid&63, lm = l&15, lq = l>>4;
  h8 bfr[2][5];
  float biasv[2];
#pragma unroll
  for (int nt=0; nt<2; ++nt){
    int oc = nt*16 + lm;
    biasv[nt] = c2b[oc];
#pragma unroll
    for (int c=0;c<5;++c){
      h8 f;
#pragma unroll
      for (int j=0;j<8;++j){
        int k = c*32 + lq*8 + j;
        int tap = k>>4, ic = k&15;
        f[j] = (_Float16)((tap<9) ? c2w[oc*144 + ic*9 + tap] : 0.f);
      }
      bfr[nt][c]=f;
    }
  }
  {
    const float* xb = x + (size_t)b*SS*FF;
    for (int i = tid; i < SS*FF/4; i += 512)
      ((float4*)xs)[i] = ((const float4*)xb)[i];
    for (int i = tid; i < 66*66; i += 512) img2[i] = (_Float16)0.f;
  }
  __syncthreads();
  {
    int ti = (tid & 31)*2, tj = (tid >> 5)*4;
    float acc[2][4];
#pragma unroll
    for (int a=0;a<2;++a)
#pragma unroll
      for (int c=0;c<4;++c) acc[a][c]=0.f;
    for (int s = 0; s < SS; ++s){
      const float* row = xs + s*FF;
      float a0 = row[ti], a1 = row[ti+1];
      float4 bv = *(const float4*)(row + tj);
      float bb2[4] = {bv.x,bv.y,bv.z,bv.w};
#pragma unroll
      for (int c=0;c<4;++c){ acc[0][c] += a0*bb2[c]; acc[1][c] += a1*bb2[c]; }
    }
    __syncthreads();
#pragma unroll
    for (int a=0;a<2;++a)
#pragma unroll
      for (int c=0;c<4;++c) img2[(ti+a+1)*66 + (tj+c+1)] = (_Float16)acc[a][c];
  }
  {
    h8 z = {0,0,0,0,0,0,0,0};
    for (int i=tid; i<(34*34+1)*3; i+=512) ((h8*)img)[i] = z;
  }
  __syncthreads();
  {
    int oc = tid>>5, slot = tid&31;
    float wr[9];
#pragma unroll
    for (int t=0;t<9;++t) wr[t]=c1w[oc*9+t];
    float bo = c1b[oc];
    for (int p=slot;p<1024;p+=32){
      int py=p>>5, px=p&31;
      int y0=py*2, x0=px*2;
      float v[4][4];
#pragma unroll
      for (int wy=0;wy<4;++wy)
#pragma unroll
        for (int wxx=0;wxx<4;++wxx) v[wy][wxx]=(float)img2[(y0+wy)*66 + x0+wxx];
      float s00=bo,s01=bo,s10=bo,s11=bo;
#pragma unroll
      for (int ky=0;ky<3;++ky)
#pragma unroll
        for (int kx=0;kx<3;++kx){
          float w=wr[ky*3+kx];
          s00 += v[ky][kx]*w;   s01 += v[ky][kx+1]*w;
          s10 += v[ky+1][kx]*w; s11 += v[ky+1][kx+1]*w;
        }
      float mx = fmaxf(fmaxf(s00,s01),fmaxf(s10,s11));
      img[((py+1)*34 + (px+1))*24 + oc] = (_Float16)fmaxf(mx,0.f);
    }
  }
  __syncthreads();
  f4v ssum0 = {0,0,0,0}, ssum1 = {0,0,0,0};
#pragma unroll 2
  for (int i=0;i<8;++i){
    int mt = wv + i*8;
    int y = mt>>1, x0 = (mt&1)*16;
    h8 afr[5];
#pragma unroll
    for (int c=0;c<5;++c){
      int tap = 2*c + (lq>>1);
      int addr;
      if (c==4 && lq>=2) addr = 34*34*24;
      else {
        int dy = tap/3 - 1, dx = tap - (tap/3)*3 - 1;
        addr = ((y+dy+1)*34 + (x0+lm+dx+1))*24 + (lq&1)*8;
      }
      afr[c] = *(const h8*)&img[addr];
    }
    f4v a0 = {biasv[0],biasv[0],biasv[0],biasv[0]};
    f4v a1 = {biasv[1],biasv[1],biasv[1],biasv[1]};
#pragma unroll
    for (int c=0;c<5;++c){
      a0 = __builtin_amdgcn_mfma_f32_16x16x32_f16(afr[c], bfr[0][c], a0, 0,0,0);
      a1 = __builtin_amdgcn_mfma_f32_16x16x32_f16(afr[c], bfr[1][c], a1, 0,0,0);
    }
#pragma unroll
    for (int r=0;r<4;++r){
      ssum0[r] += fmaxf(a0[r],0.f);
      ssum1[r] += fmaxf(a1[r],0.f);
    }
  }
  float s0 = ssum0[0]+ssum0[1]+ssum0[2]+ssum0[3];
  float s1 = ssum1[0]+ssum1[1]+ssum1[2]+ssum1[3];
  s0 += __shfl_xor(s0,16,64); s0 += __shfl_xor(s0,32,64);
  s1 += __shfl_xor(s1,16,64); s1 += __shfl_xor(s1,32,64);
  __syncthreads();
  if (lq==0){ red[wv*32+lm]=s0; red[wv*32+16+lm]=s1; }
  __syncthreads();
  if (tid<32){
    float t=0.f;
#pragma unroll
    for (int w2=0;w2<8;++w2) t += red[w2*32+tid];
    proc[b*32+tid] = t*(1.f/1024.f);
  }
}

// ====== R12: fused feature pipeline, coalesced weight staging ======
// R11 failed to move k_feat: the cost was NOT spill but uncoalesced weight
// gathers -- each per-lane fragment load (rows 256B apart) splits into ~32
// memory transactions, x ~230 instr x 8192 waves. Fix: stage all 4 weight
// matrices once per block with COALESCED reads into fragment-ordered f16 LDS
// (lane l's fragment at index l -> stride-16B ds_read_b128, conflict-free).
// Tiles shrunk to stride-64 (xt,tA) so the whole thing fits 64KB static LDS.
// Inter-layer barriers dropped: tiles are wave-private (lgkmcnt orders them).
#define TADDR(row,k) (((row)<<7) + (((((k)>>3) ^ (row)) & 15)<<3) + ((k)&7))
#define T64(row,k)   (((row)<<6) + (((((k)>>3) ^ (row)) & 7)<<3) + ((k)&7))
__global__ __launch_bounds__(256) void k_feat(const float* __restrict__ x,
    const float* __restrict__ proc,
    const float* __restrict__ fW1, const float* __restrict__ fb1,
    const float* __restrict__ fW2, const float* __restrict__ fb2,
    const float* __restrict__ cW1, const float* __restrict__ cb1,
    const float* __restrict__ cW2, const float* __restrict__ cb2,
    float* __restrict__ fw_out, _Float16* __restrict__ wxh){
  __shared__ __align__(16) _Float16 smem[32768];   // exactly 64KB
  _Float16* w1l = smem;            // 4096  (32x64  frag-ordered)
  _Float16* w2l = smem + 4096;     // 2048  (64x32)
  _Float16* w3l = smem + 6144;     // 6144  (64x96)
  _Float16* w4l = smem + 12288;    // 4096  (64x64)
  int tid = threadIdx.x, w = tid>>6, l = tid&63, lm = l&15, lq = l>>4;
  _Float16* xt = smem + 16384 + w*1024;   // [16][64] swizzled
  _Float16* tA = smem + 20480 + w*1024;   // [16][64]
  _Float16* tB = smem + 24576 + w*2048;   // [16][128]
  int b = blockIdx.x >> 1;
  size_t R0 = ((size_t)blockIdx.x*4 + w) * 16;
  // ---- cooperative coalesced weight staging (frag addr = ((mt*KC+kc)*64+l)*8) ----
  {
    int idx = tid;                      // w1: 32 rows x 8 chunks = 256
    int row = idx >> 3, ch = idx & 7;
    const float* g = fW1 + row*64 + ch*8;
    h8 f;
#pragma unroll
    for (int j=0;j<8;++j) f[j] = (_Float16)(g[j]*S_TANH);
    *(h8*)&w1l[((((row>>4)*2 + (ch>>2))*64) + (row&15) + 16*(ch&3))*8] = f;
  }
  if (tid < 256){                       // w2: 64 rows x 4 chunks = 256
    int row = tid >> 2, ch = tid & 3;
    const float* g = fW2 + row*32 + ch*8;
    h8 f;
#pragma unroll
    for (int j=0;j<8;++j) f[j] = (_Float16)(g[j]);
    *(h8*)&w2l[(((row>>4)*64) + (row&15) + 16*ch)*8] = f;
  }
  for (int idx = tid; idx < 64*12; idx += 256){   // w3: 64 x 12 = 768
    int row = idx / 12, ch = idx % 12;
    const float* g = cW1 + row*96 + ch*8;
    h8 f;
#pragma unroll
    for (int j=0;j<8;++j) f[j] = (_Float16)(g[j]*S_TANH);
    *(h8*)&w3l[((((row>>4)*3 + (ch>>2))*64) + (row&15) + 16*(ch&3))*8] = f;
  }
  for (int idx = tid; idx < 64*8; idx += 256){    // w4: 64 x 8 = 512
    int row = idx >> 3, ch = idx & 7;
    const float* g = cW2 + row*64 + ch*8;
    h8 f;
#pragma unroll
    for (int j=0;j<8;++j) f[j] = (_Float16)(g[j]);
    *(h8*)&w4l[((((row>>4)*2 + (ch>>2))*64) + (row&15) + 16*(ch&3))*8] = f;
  }
  // stage x rows (f16): lane covers row lm, feats lq*16..+15
  {
    const float* xr = x + (R0+lm)*64 + lq*16;
    float4 x0 = *(const float4*)xr;
    float4 x1 = *(const float4*)(xr+4);
    float4 x2 = *(const float4*)(xr+8);
    float4 x3 = *(const float4*)(xr+12);
    h8 hx0 = {(_Float16)x0.x,(_Float16)x0.y,(_Float16)x0.z,(_Float16)x0.w,
              (_Float16)x1.x,(_Float16)x1.y,(_Float16)x1.z,(_Float16)x1.w};
    h8 hx1 = {(_Float16)x2.x,(_Float16)x2.y,(_Float16)x2.z,(_Float16)x2.w,
              (_Float16)x3.x,(_Float16)x3.y,(_Float16)x3.z,(_Float16)x3.w};
    *(h8*)&xt[T64(lm, lq*16)] = hx0;
    *(h8*)&xt[T64(lm, lq*16+8)] = hx1;
  }
  // proc part of cmb (k=64..95), broadcast loads
  {
    float4 p0 = *(const float4*)&proc[b*32 + lq*8];
    float4 p1 = *(const float4*)&proc[b*32 + lq*8 + 4];
    h8 ph = {(_Float16)p0.x,(_Float16)p0.y,(_Float16)p0.z,(_Float16)p0.w,
             (_Float16)p1.x,(_Float16)p1.y,(_Float16)p1.z,(_Float16)p1.w};
    *(h8*)&tB[TADDR(lm, 64+lq*8)] = ph;
  }
  __syncthreads();
  // ---- L1: t1[32,16] = tanh2(W1s @ x + b1s) ----
  {
    h8 bx0 = *(const h8*)&xt[T64(lm, lq*8)];
    h8 bx1 = *(const h8*)&xt[T64(lm, 32+lq*8)];
#pragma unroll
    for (int mt=0;mt<2;++mt){
      h8 f0 = *(const h8*)&w1l[((mt*2+0)*64 + l)*8];
      h8 f1 = *(const h8*)&w1l[((mt*2+1)*64 + l)*8];
      float4 t = *(const float4*)&fb1[mt*16 + lq*4];
      f4v bv = {t.x*S_TANH, t.y*S_TANH, t.z*S_TANH, t.w*S_TANH};
      f4v a = __builtin_amdgcn_mfma_f32_16x16x32_f16(f0, bx0, bv,0,0,0);
      a = __builtin_amdgcn_mfma_f32_16x16x32_f16(f1, bx1, a,0,0,0);
      h4 tv = {(_Float16)tanh2(a[0]),(_Float16)tanh2(a[1]),
               (_Float16)tanh2(a[2]),(_Float16)tanh2(a[3])};
      *(h4*)&tA[T64(lm, mt*16+lq*4)] = tv;
    }
  }
  // ---- L2: fs[64,16] = W2 @ t1 + b2 -> cmb k=0..63 ----
  {
    h8 bt = *(const h8*)&tA[T64(lm, lq*8)];
#pragma unroll
    for (int mt=0;mt<4;++mt){
      h8 f = *(const h8*)&w2l[(mt*64 + l)*8];
      float4 t = *(const float4*)&fb2[mt*16 + lq*4];
      f4v bv = {t.x, t.y, t.z, t.w};
      f4v a = __builtin_amdgcn_mfma_f32_16x16x32_f16(f, bt, bv,0,0,0);
      h4 fv = {(_Float16)a[0],(_Float16)a[1],(_Float16)a[2],(_Float16)a[3]};
      *(h4*)&tB[TADDR(lm, mt*16+lq*4)] = fv;
    }
  }
  // ---- L3: h2[64,16] = tanh2(cW1s @ cmb + b3s) ----
  {
    h8 bc0 = *(const h8*)&tB[TADDR(lm, lq*8)];
    h8 bc1 = *(const h8*)&tB[TADDR(lm, 32+lq*8)];
    h8 bc2 = *(const h8*)&tB[TADDR(lm, 64+lq*8)];
#pragma unroll
    for (int mt=0;mt<4;++mt){
      h8 f0 = *(const h8*)&w3l[((mt*3+0)*64 + l)*8];
      h8 f1 = *(const h8*)&w3l[((mt*3+1)*64 + l)*8];
      h8 f2 = *(const h8*)&w3l[((mt*3+2)*64 + l)*8];
      float4 t = *(const float4*)&cb1[mt*16 + lq*4];
      f4v bv = {t.x*S_TANH, t.y*S_TANH, t.z*S_TANH, t.w*S_TANH};
      f4v z = {0.f,0.f,0.f,0.f};
      f4v a = __builtin_amdgcn_mfma_f32_16x16x32_f16(f0, bc0, bv,0,0,0);
      f4v c = __builtin_amdgcn_mfma_f32_16x16x32_f16(f1, bc1, z,0,0,0);
      a = __builtin_amdgcn_mfma_f32_16x16x32_f16(f2, bc2, a,0,0,0);
      a = a + c;
      h4 hv = {(_Float16)tanh2(a[0]),(_Float16)tanh2(a[1]),
               (_Float16)tanh2(a[2]),(_Float16)tanh2(a[3])};
      *(h4*)&tA[T64(lm, mt*16+lq*4)] = hv;
    }
  }
  // ---- L4: aw[64,16] = cW2 @ h2 + b4; softmax_m; outputs ----
  f4v a4[4];
  {
    h8 bh0 = *(const h8*)&tA[T64(lm, lq*8)];
    h8 bh1 = *(const h8*)&tA[T64(lm, 32+lq*8)];
#pragma unroll
    for (int mt=0;mt<4;++mt){
      h8 f0 = *(const h8*)&w4l[((mt*2+0)*64 + l)*8];
      h8 f1 = *(const h8*)&w4l[((mt*2+1)*64 + l)*8];
      float4 t = *(const float4*)&cb2[mt*16 + lq*4];
      f4v bv = {t.x, t.y, t.z, t.w};
      f4v a = __builtin_amdgcn_mfma_f32_16x16x32_f16(f0, bh0, bv,0,0,0);
      a4[mt] = __builtin_amdgcn_mfma_f32_16x16x32_f16(f1, bh1, a,0,0,0);
    }
  }
  float mx = a4[0][0];
#pragma unroll
  for (int mt=0;mt<4;++mt)
#pragma unroll
    for (int r=0;r<4;++r) mx = fmaxf(mx, a4[mt][r]);
  mx = fmaxf(mx, __shfl_xor(mx,16,64));
  mx = fmaxf(mx, __shfl_xor(mx,32,64));
  f4v e4[4];
  float s = 0.f;
#pragma unroll
  for (int mt=0;mt<4;++mt)
#pragma unroll
    for (int r=0;r<4;++r){
      float e = fexp2((a4[mt][r]-mx)*LOG2E);
      e4[mt][r] = e; s += e;
    }
  s += __shfl_xor(s,16,64);
  s += __shfl_xor(s,32,64);
  float rs = frcp(s);
#pragma unroll
  for (int mt=0;mt<4;++mt){
    h4 xh = *(const h4*)&xt[T64(lm, mt*16+lq*4)];
    float4 fwv;
    fwv.x = e4[mt][0]*rs; fwv.y = e4[mt][1]*rs;
    fwv.z = e4[mt][2]*rs; fwv.w = e4[mt][3]*rs;
    h4 wh = {(_Float16)((float)xh[0]*fwv.x), (_Float16)((float)xh[1]*fwv.y),
             (_Float16)((float)xh[2]*fwv.z), (_Float16)((float)xh[3]*fwv.w)};
    size_t off = (R0+lm)*64 + mt*16 + lq*4;
    *(float4*)&fw_out[off] = fwv;
    *(h4*)&wxh[off] = wh;
  }
}

// ================= MFMA encoder LSTM (swapped operands) =================
// ench: f16 copy of enc, row-padded to 112 (units 100..111 zeroed).
__global__ __launch_bounds__(448) void k_enc_mfma(const _Float16* __restrict__ wxh,
    const float* __restrict__ Wih, const float* __restrict__ Whh,
    const float* __restrict__ bih, const float* __restrict__ bhh,
    _Float16* __restrict__ ench){
  __shared__ __align__(16) _Float16 hbuf[2][16*128];
  __shared__ __align__(16) _Float16 xst[2][16*64];
  int tid = threadIdx.x;
  int w = tid >> 6, l = tid & 63;
  int lm = l & 15, lq = l >> 4;
  int b0 = blockIdx.x * 16;
  int au = w*16 + lm;
  bool avalid = au < 100;
  int u0 = w*16 + lq*4;
  bool uvalid = (u0 + 3) < 100;
  const float gsc[4] = {S_SIG, S_SIG, S_TANH, S_SIG};   // gate order i,f,g,o
  h8 wfr[4][6];
#pragma unroll
  for (int tt=0; tt<4; ++tt){
    int row = tt*100 + au;
#pragma unroll
    for (int cc=0; cc<6; ++cc){
      h8 f;
#pragma unroll
      for (int j=0;j<8;++j){
        int kg = cc*32 + lq*8 + j;
        float v = 0.f;
        if (avalid){
          if (kg < 64) v = Wih[(size_t)row*64 + kg];
          else { int kh = kg - 64; if (kh < 100) v = Whh[(size_t)row*100 + kh]; }
        }
        f[j] = (_Float16)(v*gsc[tt]);
      }
      wfr[tt][cc] = f;
    }
  }
  f4v biasv[4];
#pragma unroll
  for (int tt=0; tt<4; ++tt){
    if (uvalid){
      float4 bi = *(const float4*)&bih[tt*100 + u0];
      float4 bh = *(const float4*)&bhh[tt*100 + u0];
      float s = gsc[tt];
      f4v bv2 = {(bi.x+bh.x)*s, (bi.y+bh.y)*s, (bi.z+bh.z)*s, (bi.w+bh.w)*s};
      biasv[tt] = bv2;
    } else { f4v z = {0,0,0,0}; biasv[tt] = z; }
  }
  for (int i = tid; i < 2*16*128; i += 448) hbuf[0][i] = (_Float16)0.f;
  int sm = tid >> 4, skq = tid & 15;
  bool doPref = (tid < 256);
  int xwaddr = sm*64 + (((skq>>1) ^ (sm&7))<<3) + (skq&1)*4;
  h4 rA, rB;
  if (doPref){
    *(h4*)&xst[0][xwaddr] = *(const h4*)(wxh + ((size_t)(b0+sm)*SS + 0)*FF + skq*4);
    rA = *(const h4*)(wxh + ((size_t)(b0+sm)*SS + 1)*FF + skq*4);   // x(1)
  }
  float cst[4] = {0.f,0.f,0.f,0.f};   // pre-scaled cell state (c * 2/ln2)
  int hwaddr = lm*128 + (((2*w + (lq>>1)) ^ (lm&7))<<3) + (lq&1)*4;
  __syncthreads();

#define ENC_STEP(T, CUR, RCONS, RISSUE)                                          \
  {                                                                              \
    const int cur = (CUR), nxt = (CUR)^1;                                        \
    if (doPref && (T) < SS-2)                                                    \
      RISSUE = *(const h4*)(wxh + ((size_t)(b0+sm)*SS + ((T)+2))*FF + skq*4);    \
    h8 bact[6];                                                                  \
    _Pragma("unroll")                                                            \
    for (int cc=0; cc<2; ++cc)                                                   \
      bact[cc] = *(const h8*)&xst[cur][lm*64 + (((cc*4+lq) ^ (lm&7))<<3)];       \
    _Pragma("unroll")                                                            \
    for (int cc=0; cc<4; ++cc)                                                   \
      bact[2+cc] = *(const h8*)&hbuf[cur][lm*128 + (((cc*4+lq) ^ (lm&7))<<3)];   \
    f4v acc[4];                                                                  \
    __builtin_amdgcn_s_setprio(1);                                               \
    _Pragma("unroll")                                                            \
    for (int tt=0; tt<4; ++tt){                                                  \
      f4v a1 = biasv[tt];                                                        \
      f4v a2 = {0.f,0.f,0.f,0.f};                                                \
      a1 = __builtin_amdgcn_mfma_f32_16x16x32_f16(wfr[tt][0], bact[0], a1, 0,0,0); \
      a2 = __builtin_amdgcn_mfma_f32_16x16x32_f16(wfr[tt][1], bact[1], a2, 0,0,0); \
      a1 = __builtin_amdgcn_mfma_f32_16x16x32_f16(wfr[tt][2], bact[2], a1, 0,0,0); \
      a2 = __builtin_amdgcn_mfma_f32_16x16x32_f16(wfr[tt][3], bact[3], a2, 0,0,0); \
      a1 = __builtin_amdgcn_mfma_f32_16x16x32_f16(wfr[tt][4], bact[4], a1, 0,0,0); \
      a2 = __builtin_amdgcn_mfma_f32_16x16x32_f16(wfr[tt][5], bact[5], a2, 0,0,0); \
      acc[tt] = a1 + a2;                                                         \
    }                                                                            \
    __builtin_amdgcn_s_setprio(0);                                               \
    float hn[4];                                                                 \
    _Pragma("unroll")                                                            \
    for (int r=0;r<4;++r){                                                       \
      float Ei = fexp2(acc[0][r]), Ef = fexp2(acc[1][r]);                        \
      float Eg = fexp2(acc[2][r]), Eo = fexp2(acc[3][r]);                        \
      float cn2 = frcp(1.f+Ef)*cst[r] + sigtanhT(Ei, Eg);                        \
      float Ec = fexp2(cn2);                                                     \
      hn[r] = sigtanh(Eo, Ec);                                                   \
      cst[r] = cn2;                                                              \
    }                                                                            \
    if (uvalid){                                                                 \
      h4 hp = {(_Float16)hn[0],(_Float16)hn[1],(_Float16)hn[2],(_Float16)hn[3]}; \
      *(h4*)&hbuf[nxt][hwaddr] = hp;                                             \
      *(h4*)&ench[((size_t)(b0+lm)*SS + (T))*112 + u0] = hp;                     \
    } else {                                                                     \
      h4 z = {(_Float16)0.f,(_Float16)0.f,(_Float16)0.f,(_Float16)0.f};          \
      *(h4*)&ench[((size_t)(b0+lm)*SS + (T))*112 + u0] = z;                      \
    }                                                                            \
    if (doPref && (T) < SS-1){                                                   \
      *(h4*)&xst[nxt][xwaddr] = RCONS;                                           \
    }                                                                            \
    LDS_BARRIER();                                                               \
  }

  for (int t = 0; t < SS; t += 2){
    ENC_STEP(t,   0, rA, rB)
    ENC_STEP(t+1, 1, rB, rA)
  }
#undef ENC_STEP
}

// ====== ts GEMM + attn2 FUSED (one block per batch) ======
// R12: aW1 staged coalesced into fragment-ordered f16 LDS (K zero-padded to
// 128) -> 16 ds_read_b128 per lane instead of 128 scattered global gathers.
__global__ __launch_bounds__(256) void k_tsattn2(const _Float16* __restrict__ ench,
    const float* __restrict__ aW1, const float* __restrict__ ab1,
    const float* __restrict__ aW2, const float* __restrict__ ab2,
    const float* __restrict__ bW, const float* __restrict__ bb_,
    const float* __restrict__ h0W, const float* __restrict__ h0b,
    const float* __restrict__ c0W, const float* __restrict__ c0b,
    const float* __restrict__ dWih, const float* __restrict__ dbih, const float* __restrict__ dbhh,
    float* __restrict__ tw_out, float* __restrict__ dh0, float* __restrict__ dc0,
    float* __restrict__ decpre){
  __shared__ __align__(16) _Float16 awl[64*128];   // 16KB frag-ordered
  __shared__ float tsb[SS];
  __shared__ float ctxb[HH];
  __shared__ float ctx2[200];
  __shared__ float bottb[32];
  __shared__ float red[8];
  int tid = threadIdx.x, wv = tid>>6, lane = tid&63, lm = lane&15, lq = lane>>4;
  int b = blockIdx.x;
  // stage aW1 (scaled, padded): 64 rows x 16 chunks of 8
  for (int idx = tid; idx < 64*16; idx += 256){
    int row = idx >> 4, ch = idx & 15;
    h8 f;
#pragma unroll
    for (int j=0;j<8;++j){
      int k = ch*8 + j;
      f[j] = (_Float16)((k<100) ? aW1[row*100+k]*S_TANH : 0.f);
    }
    *(h8*)&awl[((((row>>4)*4 + (ch>>2))*64) + (row&15) + 16*(ch&3))*8] = f;
  }
  __syncthreads();
  {
    float ab1v[4], aw2v[4];
#pragma unroll
    for (int nt=0; nt<4; ++nt){ ab1v[nt] = ab1[nt*16+lm]*S_TANH; aw2v[nt] = aW2[nt*16+lm]; }
    float ab2v = ab2[0];
#pragma unroll
    for (int i=0;i<2;++i){
      int M0 = b*SS + wv*32 + i*16;
      const _Float16* rowp = ench + (size_t)(M0+lm)*112;
      h8 afr[4];
#pragma unroll
      for (int cc=0; cc<3; ++cc)
        afr[cc] = *(const h8*)(rowp + cc*32 + lq*8);
      if (lq < 2) afr[3] = *(const h8*)(rowp + 96 + lq*8);
      else { h8 z={0,0,0,0,0,0,0,0}; afr[3]=z; }
      f4v acc[4];
#pragma unroll
      for (int nt=0; nt<4; ++nt){
        f4v a = {ab1v[nt],ab1v[nt],ab1v[nt],ab1v[nt]};
#pragma unroll
        for (int cc=0; cc<4; ++cc){
          h8 bf = *(const h8*)&awl[((nt*4+cc)*64 + lane)*8];
          a = __builtin_amdgcn_mfma_f32_16x16x32_f16(afr[cc], bf, a, 0,0,0);
        }
        acc[nt]=a;
      }
      float p[4];
#pragma unroll
      for (int r=0;r<4;++r){
        p[r] = aw2v[0]*tanh2(acc[0][r]) + aw2v[1]*tanh2(acc[1][r])
             + aw2v[2]*tanh2(acc[2][r]) + aw2v[3]*tanh2(acc[3][r]);
#pragma unroll
        for (int m=1;m<16;m<<=1) p[r] += __shfl_xor(p[r], m, 64);
      }
      if (lm==0){
        float4 st; st.x=p[0]+ab2v; st.y=p[1]+ab2v; st.z=p[2]+ab2v; st.w=p[3]+ab2v;
        *(float4*)&tsb[wv*32 + i*16 + lq*4] = st;
      }
    }
  }
  __syncthreads();
  const _Float16* encb = ench + (size_t)b*SS*112;
  float tv = (tid < SS) ? tsb[tid] : -1e30f;
  float m = wmax(tv);
  if (lane==0) red[wv]=m;
  __syncthreads();
  m = fmaxf(fmaxf(red[0],red[1]), fmaxf(red[2],red[3]));
  float e = (tid < SS) ? __expf(tv - m) : 0.f;
  float sm = wsum(e);
  if (lane==0) red[4+wv]=sm;
  __syncthreads();
  float denom = red[4]+red[5]+red[6]+red[7];
  float rden = frcp(denom);
  if (tid < SS){
    float twv = e*rden;
    tw_out[(size_t)b*SS + tid] = twv;
    tsb[tid] = twv;
  }
  __syncthreads();
  if (tid < 200){
    int u = (tid < 100) ? tid : (tid - 100);
    int sb = (tid < 100) ? 0 : 64;
    const _Float16* ep = encb + (size_t)sb*112 + u;
    const float* tp = tsb + sb;
    float a = 0.f;
#pragma unroll 4
    for (int s=0;s<64;++s) a += tp[s]*(float)ep[s*112];
    ctx2[tid] = a;
  }
  __syncthreads();
  if (tid < HH) ctxb[tid] = ctx2[tid] + ctx2[tid+100];
  __syncthreads();
  if (tid < 32){
    float a = bb_[tid];
    const float* wr = bW + tid*HH;
    for (int k=0;k<HH;++k) a += wr[k]*ctxb[k];
    bottb[tid]=a;
  }
  __syncthreads();
  if (tid < HH){
    float a = h0b[tid];
    const float* wr = h0W + tid*32;
#pragma unroll
    for (int k=0;k<32;++k) a += wr[k]*bottb[k];
    dh0[(size_t)b*HH + tid] = a;
  } else if (tid < 200){
    int jj = tid-100;
    float a = c0b[jj];
    const float* wr = c0W + jj*32;
#pragma unroll
    for (int k=0;k<32;++k) a += wr[k]*bottb[k];
    dc0[(size_t)b*HH + jj] = a;
  }
  {
    int jj = tid;
    float a = dbih[jj]+dbhh[jj];
    const float* wr = dWih + jj*32;
#pragma unroll
    for (int k=0;k<32;++k) a += wr[k]*bottb[k];
    decpre[(size_t)b*400 + jj] = a;
    jj = tid + 256;
    if (jj < 400){
      float a2v = dbih[jj]+dbhh[jj];
      const float* wr2 = dWih + jj*32;
#pragma unroll
      for (int k=0;k<32;++k) a2v += wr2[k]*bottb[k];
      decpre[(size_t)b*400 + jj] = a2v;
    }
  }
}

// ================= MFMA decoder LSTM (swapped operands) =================
__global__ __launch_bounds__(448) void k_dec_mfma(const float* __restrict__ decpre,
    const float* __restrict__ Whh,
    const float* __restrict__ dh0, const float* __restrict__ dc0,
    _Float16* __restrict__ dech){
  __shared__ __align__(16) _Float16 hbuf[2][16*128];
  int tid = threadIdx.x;
  int w = tid >> 6, l = tid & 63;
  int lm = l & 15, lq = l >> 4;
  int b0 = blockIdx.x * 16;
  int au = w*16 + lm;
  bool avalid = au < 100;
  int u0 = w*16 + lq*4;
  bool uvalid = (u0 + 3) < 100;
  const float gsc[4] = {S_SIG, S_SIG, S_TANH, S_SIG};
  h8 wfr[4][4];
#pragma unroll
  for (int tt = 0; tt < 4; ++tt){
    int row = tt*100 + au;
#pragma unroll
    for (int cc = 0; cc < 4; ++cc){
      h8 f;
#pragma unroll
      for (int j = 0; j < 8; ++j){
        int kh = cc*32 + lq*8 + j;
        float v = (avalid && kh < 100) ? Whh[(size_t)row*100 + kh] : 0.f;
        f[j] = (_Float16)(v*gsc[tt]);
      }
      wfr[tt][cc] = f;
    }
  }
  f4v pre[4];
  float cst[4] = {0.f,0.f,0.f,0.f};
  if (uvalid){
#pragma unroll
    for (int tt = 0; tt < 4; ++tt){
      float4 p = *(const float4*)&decpre[(size_t)(b0+lm)*400 + tt*100 + u0];
      float s = gsc[tt];
      f4v pv = {p.x*s, p.y*s, p.z*s, p.w*s};
      pre[tt] = pv;
    }
    float4 c4 = *(const float4*)&dc0[(size_t)(b0+lm)*100 + u0];
    cst[0]=c4.x*S_TANH; cst[1]=c4.y*S_TANH; cst[2]=c4.z*S_TANH; cst[3]=c4.w*S_TANH;
  } else {
    f4v z = {0,0,0,0};
#pragma unroll
    for (int tt = 0; tt < 4; ++tt) pre[tt] = z;
  }
  for (int i = tid; i < 16*128; i += 448) hbuf[1][i] = (_Float16)0.f;
  for (int idx = tid; idx < 16*128; idx += 448){
    int m = idx >> 7, u2 = idx & 127;
    float v = (u2 < 100) ? dh0[(size_t)(b0+m)*HH + u2] : 0.f;
    hbuf[0][m*128 + (((u2>>3) ^ (m&7))<<3) + (u2&7)] = (_Float16)v;
  }
  int hwaddr = lm*128 + (((2*w + (lq>>1)) ^ (lm&7))<<3) + (lq&1)*4;
  __syncthreads();

#define DEC_STEP(T, CUR)                                                         \
  {                                                                              \
    const int cur = (CUR), nxt = (CUR)^1;                                        \
    h8 bact[4];                                                                  \
    _Pragma("unroll")                                                            \
    for (int cc = 0; cc < 4; ++cc)                                               \
      bact[cc] = *(const h8*)&hbuf[cur][lm*128 + (((cc*4+lq) ^ (lm&7))<<3)];     \
    f4v acc[4];                                                                  \
    __builtin_amdgcn_s_setprio(1);                                               \
    _Pragma("unroll")                                                            \
    for (int tt = 0; tt < 4; ++tt){                                              \
      f4v a1 = pre[tt];                                                          \
      f4v a2 = {0.f,0.f,0.f,0.f};                                                \
      a1 = __builtin_amdgcn_mfma_f32_16x16x32_f16(wfr[tt][0], bact[0], a1, 0,0,0); \
      a2 = __builtin_amdgcn_mfma_f32_16x16x32_f16(wfr[tt][1], bact[1], a2, 0,0,0); \
      a1 = __builtin_amdgcn_mfma_f32_16x16x32_f16(wfr[tt][2], bact[2], a1, 0,0,0); \
      a2 = __builtin_amdgcn_mfma_f32_16x16x32_f16(wfr[tt][3], bact[3], a2, 0,0,0); \
      acc[tt] = a1 + a2;                                                         \
    }                                                                            \
    __builtin_amdgcn_s_setprio(0);                                               \
    float hn[4];                                                                 \
    _Pragma("unroll")                                                            \
    for (int r=0;r<4;++r){                                                       \
      float Ei = fexp2(acc[0][r]), Ef = fexp2(acc[1][r]);                        \
      float Eg = fexp2(acc[2][r]), Eo = fexp2(acc[3][r]);                        \
      float cn2 = frcp(1.f+Ef)*cst[r] + sigtanhT(Ei, Eg);                        \
      float Ec = fexp2(cn2);                                                     \
      hn[r] = sigtanh(Eo, Ec);                                                   \
      cst[r] = cn2;                                                              \
    }                                                                            \
    if (uvalid){                                                                 \
      h4 hp = {(_Float16)hn[0],(_Float16)hn[1],(_Float16)hn[2],(_Float16)hn[3]}; \
      *(h4*)&hbuf[nxt][hwaddr] = hp;                                             \
      *(h4*)&dech[((size_t)(b0+lm)*SS + (T))*112 + u0] = hp;                     \
    } else {                                                                     \
      h4 z = {(_Float16)0.f,(_Float16)0.f,(_Float16)0.f,(_Float16)0.f};          \
      *(h4*)&dech[((size_t)(b0+lm)*SS + (T))*112 + u0] = z;                      \
    }                                                                            \
    LDS_BARRIER();                                                               \
  }

  for (int t = 0; t < SS; t += 2){
    DEC_STEP(t,   0)
    DEC_STEP(t+1, 1)
  }
#undef DEC_STEP
}

// ------------- out = dech @ oW^T + ob, MFMA -------------
// R12: oW staged coalesced into fragment-ordered f16 LDS (padded to 128).
__global__ __launch_bounds__(256) void k_out(const _Float16* __restrict__ dech,
    const float* __restrict__ oW, const float* __restrict__ ob, float* __restrict__ out0){
  __shared__ __align__(16) _Float16 owl[64*128];   // 16KB frag-ordered
  int tid = threadIdx.x, wv = tid>>6, l = tid&63, lm = l&15, lq = l>>4;
  for (int idx = tid; idx < 64*16; idx += 256){
    int row = idx >> 4, ch = idx & 15;
    h8 f;
#pragma unroll
    for (int j=0;j<8;++j){
      int k = ch*8 + j;
      f[j] = (_Float16)((k<100) ? oW[row*100+k] : 0.f);
    }
    *(h8*)&owl[((((row>>4)*4 + (ch>>2))*64) + (row&15) + 16*(ch&3))*8] = f;
  }
  __syncthreads();
  float obv[4];
#pragma unroll
  for (int nt=0; nt<4; ++nt) obv[nt] = ob[nt*16+lm];
  int tile0 = (blockIdx.x*4 + wv)*4;
#pragma unroll
  for (int i=0;i<4;++i){
    int M0 = (tile0+i)*16;
    const _Float16* rowp = dech + (size_t)(M0+lm)*112;
    h8 afr[4];
#pragma unroll
    for (int cc=0; cc<3; ++cc)
      afr[cc] = *(const h8*)(rowp + cc*32 + lq*8);
    if (lq < 2) afr[3] = *(const h8*)(rowp + 96 + lq*8);
    else { h8 z={0,0,0,0,0,0,0,0}; afr[3]=z; }
#pragma unroll
    for (int nt=0; nt<4; ++nt){
      f4v a = {obv[nt],obv[nt],obv[nt],obv[nt]};
#pragma unroll
      for (int cc=0; cc<4; ++cc){
        h8 bf = *(const h8*)&owl[((nt*4+cc)*64 + l)*8];
        a = __builtin_amdgcn_mfma_f32_16x16x32_f16(afr[cc], bf, a, 0,0,0);
      }
#pragma unroll
      for (int r=0;r<4;++r)
        out0[(size_t)(M0 + lq*4 + r)*64 + nt*16 + lm] = a[r];
    }
  }
}

extern "C" void kernel_launch(void* const* d_in, const int* in_sizes, int n_in,
                              void* d_out, int out_size, void* d_ws, size_t ws_size,
                              hipStream_t stream) {
  const float* x    = (const float*)d_in[0];
  const float* c1w  = (const float*)d_in[1];
  const float* c1b  = (const float*)d_in[2];
  const float* c2w  = (const float*)d_in[3];
  const float* c2b  = (const float*)d_in[4];
  const float* fW1  = (const float*)d_in[5];
  const float* fb1  = (const float*)d_in[6];
  const float* fW2  = (const float*)d_in[7];
  const float* fb2  = (const float*)d_in[8];
  const float* cW1  = (const float*)d_in[9];
  const float* cb1  = (const float*)d_in[10];
  const float* cW2  = (const float*)d_in[11];
  const float* cb2  = (const float*)d_in[12];
  const float* eWih = (const float*)d_in[13];
  const float* eWhh = (const float*)d_in[14];
  const float* ebih = (const float*)d_in[15];
  const float* ebhh = (const float*)d_in[16];
  const float* aW1  = (const float*)d_in[17];
  const float* ab1  = (const float*)d_in[18];
  const float* aW2  = (const float*)d_in[19];
  const float* ab2  = (const float*)d_in[20];
  const float* bW   = (const float*)d_in[21];
  const float* bb   = (const float*)d_in[22];
  const float* h0W  = (const float*)d_in[23];
  const float* h0b  = (const float*)d_in[24];
  const float* c0W  = (const float*)d_in[25];
  const float* c0b  = (const float*)d_in[26];
  const float* dWih = (const float*)d_in[27];
  const float* dWhh = (const float*)d_in[28];
  const float* dbih = (const float*)d_in[29];
  const float* dbhh = (const float*)d_in[30];
  const float* oW   = (const float*)d_in[31];
  const float* ob   = (const float*)d_in[32];

  float* out0   = (float*)d_out;
  float* out_tw = out0 + (size_t)BB*SS*FF;
  float* out_fw = out_tw + (size_t)BB*SS;

  char* ws = (char*)d_ws;
  float*  proc   = (float*) (ws + 50331648);    // 0.13 MB
  _Float16* wxh  = (_Float16*)(ws + 84017152);  // 16.78 MB (f16, [b*S+s][64])
  float*  dh0    = (float*) (ws + 170000384);   // 0.41 MB
  float*  dc0    = (float*) (ws + 170409984);   // 0.41 MB
  float*  decpre = (float*) (ws + 170819584);   // 1.64 MB
  _Float16* dech = (_Float16*)(ws + 172457984); // 29.36 MB (f16, [row][112])
  _Float16* ench = (_Float16*)(ws + 50462720);  // 29.36 MB

  k_conv<<<BB, 512, 0, stream>>>(x, c1w, c1b, c2w, c2b, proc);
  k_feat<<<2048, 256, 0, stream>>>(x, proc, fW1, fb1, fW2, fb2,
                                   cW1, cb1, cW2, cb2, out_fw, wxh);
  k_enc_mfma<<<64, 448, 0, stream>>>(wxh, eWih, eWhh, ebih, ebhh, ench);
  k_tsattn2<<<BB, 256, 0, stream>>>(ench, aW1, ab1, aW2, ab2, bW, bb,
                                    h0W, h0b, c0W, c0b,
                                    dWih, dbih, dbhh, out_tw, dh0, dc0, decpre);
  k_dec_mfma<<<64, 448, 0, stream>>>(decpre, dWhh, dh0, dc0, dech);
  k_out<<<512, 256, 0, stream>>>(dech, oW, ob, out0);
}

// Round 13
// 587.504 us; speedup vs baseline: 1.0753x; 1.0140x over previous
//
#include <hip/hip_runtime.h>
#include <hip/hip_fp16.h>

#define BB 1024
#define SS 128
#define FF 64
#define HH 100

typedef _Float16 h8 __attribute__((ext_vector_type(8)));
typedef _Float16 h4 __attribute__((ext_vector_type(4)));
typedef float f4v __attribute__((ext_vector_type(4)));

// --- fast transcendentals ---------------------------------------------------
#define S_SIG  (-1.4426950408889634f)   // i,f,o rows: acc = -z/ln2
#define S_TANH ( 2.8853900817779268f)   // g rows:     acc = 2z/ln2
#define LOG2E  ( 1.4426950408889634f)
__device__ __forceinline__ float frcp(float x){ return __builtin_amdgcn_rcpf(x); }
__device__ __forceinline__ float fexp2(float x){ return __builtin_amdgcn_exp2f(x); }
__device__ __forceinline__ float sigm2(float a){ return frcp(1.f + fexp2(a)); }
__device__ __forceinline__ float tanh2(float a){ return 1.f - 2.f*frcp(fexp2(a)+1.f);}
__device__ __forceinline__ float ftanh(float x){ return tanh2(x*S_TANH); }
__device__ __forceinline__ float sigtanh(float Ei, float Et){
  float D = __builtin_fmaf(Ei, Et, Ei) + (Et + 1.f);
  return (Et - 1.f) * frcp(D);
}
__device__ __forceinline__ float sigtanhT(float Ei, float Et){
  float D = __builtin_fmaf(Ei, Et, Ei) + (Et + 1.f);
  return __builtin_fmaf(S_TANH, Et, -S_TANH) * frcp(D);
}

#define LDS_BARRIER() __asm__ __volatile__("s_waitcnt lgkmcnt(0)\ns_barrier" ::: "memory")

__device__ __forceinline__ float wsum(float v){
#pragma unroll
  for (int m = 32; m >= 1; m >>= 1) v += __shfl_xor(v, m, 64);
  return v;
}
__device__ __forceinline__ float wmax(float v){
#pragma unroll
  for (int m = 32; m >= 1; m >>= 1) v = fmaxf(v, __shfl_xor(v, m, 64));
  return v;
}

// ====== gram + conv1pool + conv2 + mean FUSED (one block per batch) ======
__global__ __launch_bounds__(512) void k_conv(const float* __restrict__ x,
    const float* __restrict__ c1w, const float* __restrict__ c1b,
    const float* __restrict__ c2w, const float* __restrict__ c2b,
    float* __restrict__ proc){
  __shared__ __align__(16) char smem[64256];
  _Float16* img2 = (_Float16*)smem;              // 8712 B
  float*    xs   = (float*)(smem + 8720);        // 32768 B (dies at img zero)
  _Float16* img  = (_Float16*)(smem + 8720);     // 55536 B
  float*    red  = (float*)smem;                 // 1024 B (alias img2, late)
  int tid = threadIdx.x, b = blockIdx.x;
  int wv = tid>>6, l = tid&63, lm = l&15, lq = l>>4;
  h8 bfr[2][5];
  float biasv[2];
#pragma unroll
  for (int nt=0; nt<2; ++nt){
    int oc = nt*16 + lm;
    biasv[nt] = c2b[oc];
#pragma unroll
    for (int c=0;c<5;++c){
      h8 f;
#pragma unroll
      for (int j=0;j<8;++j){
        int k = c*32 + lq*8 + j;
        int tap = k>>4, ic = k&15;
        f[j] = (_Float16)((tap<9) ? c2w[oc*144 + ic*9 + tap] : 0.f);
      }
      bfr[nt][c]=f;
    }
  }
  {
    const float* xb = x + (size_t)b*SS*FF;
    for (int i = tid; i < SS*FF/4; i += 512)
      ((float4*)xs)[i] = ((const float4*)xb)[i];
    for (int i = tid; i < 66*66; i += 512) img2[i] = (_Float16)0.f;
  }
  __syncthreads();
  {
    int ti = (tid & 31)*2, tj = (tid >> 5)*4;
    float acc[2][4];
#pragma unroll
    for (int a=0;a<2;++a)
#pragma unroll
      for (int c=0;c<4;++c) acc[a][c]=0.f;
    for (int s = 0; s < SS; ++s){
      const float* row = xs + s*FF;
      float a0 = row[ti], a1 = row[ti+1];
      float4 bv = *(const float4*)(row + tj);
      float bb2[4] = {bv.x,bv.y,bv.z,bv.w};
#pragma unroll
      for (int c=0;c<4;++c){ acc[0][c] += a0*bb2[c]; acc[1][c] += a1*bb2[c]; }
    }
    __syncthreads();
#pragma unroll
    for (int a=0;a<2;++a)
#pragma unroll
      for (int c=0;c<4;++c) img2[(ti+a+1)*66 + (tj+c+1)] = (_Float16)acc[a][c];
  }
  {
    h8 z = {0,0,0,0,0,0,0,0};
    for (int i=tid; i<(34*34+1)*3; i+=512) ((h8*)img)[i] = z;
  }
  __syncthreads();
  {
    int oc = tid>>5, slot = tid&31;
    float wr[9];
#pragma unroll
    for (int t=0;t<9;++t) wr[t]=c1w[oc*9+t];
    float bo = c1b[oc];
    for (int p=slot;p<1024;p+=32){
      int py=p>>5, px=p&31;
      int y0=py*2, x0=px*2;
      float v[4][4];
#pragma unroll
      for (int wy=0;wy<4;++wy)
#pragma unroll
        for (int wxx=0;wxx<4;++wxx) v[wy][wxx]=(float)img2[(y0+wy)*66 + x0+wxx];
      float s00=bo,s01=bo,s10=bo,s11=bo;
#pragma unroll
      for (int ky=0;ky<3;++ky)
#pragma unroll
        for (int kx=0;kx<3;++kx){
          float w=wr[ky*3+kx];
          s00 += v[ky][kx]*w;   s01 += v[ky][kx+1]*w;
          s10 += v[ky+1][kx]*w; s11 += v[ky+1][kx+1]*w;
        }
      float mx = fmaxf(fmaxf(s00,s01),fmaxf(s10,s11));
      img[((py+1)*34 + (px+1))*24 + oc] = (_Float16)fmaxf(mx,0.f);
    }
  }
  __syncthreads();
  f4v ssum0 = {0,0,0,0}, ssum1 = {0,0,0,0};
#pragma unroll 2
  for (int i=0;i<8;++i){
    int mt = wv + i*8;
    int y = mt>>1, x0 = (mt&1)*16;
    h8 afr[5];
#pragma unroll
    for (int c=0;c<5;++c){
      int tap = 2*c + (lq>>1);
      int addr;
      if (c==4 && lq>=2) addr = 34*34*24;
      else {
        int dy = tap/3 - 1, dx = tap - (tap/3)*3 - 1;
        addr = ((y+dy+1)*34 + (x0+lm+dx+1))*24 + (lq&1)*8;
      }
      afr[c] = *(const h8*)&img[addr];
    }
    f4v a0 = {biasv[0],biasv[0],biasv[0],biasv[0]};
    f4v a1 = {biasv[1],biasv[1],biasv[1],biasv[1]};
#pragma unroll
    for (int c=0;c<5;++c){
      a0 = __builtin_amdgcn_mfma_f32_16x16x32_f16(afr[c], bfr[0][c], a0, 0,0,0);
      a1 = __builtin_amdgcn_mfma_f32_16x16x32_f16(afr[c], bfr[1][c], a1, 0,0,0);
    }
#pragma unroll
    for (int r=0;r<4;++r){
      ssum0[r] += fmaxf(a0[r],0.f);
      ssum1[r] += fmaxf(a1[r],0.f);
    }
  }
  float s0 = ssum0[0]+ssum0[1]+ssum0[2]+ssum0[3];
  float s1 = ssum1[0]+ssum1[1]+ssum1[2]+ssum1[3];
  s0 += __shfl_xor(s0,16,64); s0 += __shfl_xor(s0,32,64);
  s1 += __shfl_xor(s1,16,64); s1 += __shfl_xor(s1,32,64);
  __syncthreads();
  if (lq==0){ red[wv*32+lm]=s0; red[wv*32+16+lm]=s1; }
  __syncthreads();
  if (tid<32){
    float t=0.f;
#pragma unroll
    for (int w2=0;w2<8;++w2) t += red[w2*32+tid];
    proc[b*32+tid] = t*(1.f/1024.f);
  }
}

// ====== R13: fused feature pipeline, 512 threads (1 batch/block) ======
// 8 waves x 16 rows = 128 rows; weight staging now 1024x instead of 2048x.
// 96KB LDS -> 1 block/CU x 8 waves = same 8 waves/CU as the R12 layout.
#define TADDR(row,k) (((row)<<7) + (((((k)>>3) ^ (row)) & 15)<<3) + ((k)&7))
#define T64(row,k)   (((row)<<6) + (((((k)>>3) ^ (row)) & 7)<<3) + ((k)&7))
__global__ __launch_bounds__(512) void k_feat(const float* __restrict__ x,
    const float* __restrict__ proc,
    const float* __restrict__ fW1, const float* __restrict__ fb1,
    const float* __restrict__ fW2, const float* __restrict__ fb2,
    const float* __restrict__ cW1, const float* __restrict__ cb1,
    const float* __restrict__ cW2, const float* __restrict__ cb2,
    float* __restrict__ fw_out, _Float16* __restrict__ wxh){
  __shared__ __align__(16) _Float16 smem[49152];   // 96KB
  _Float16* w1l = smem;            // 4096
  _Float16* w2l = smem + 4096;     // 2048
  _Float16* w3l = smem + 6144;     // 6144
  _Float16* w4l = smem + 12288;    // 4096
  int tid = threadIdx.x, w = tid>>6, l = tid&63, lm = l&15, lq = l>>4;
  _Float16* xt = smem + 16384 + w*1024;   // [16][64] swizzled
  _Float16* tA = smem + 24576 + w*1024;   // [16][64]
  _Float16* tB = smem + 32768 + w*2048;   // [16][128]
  int b = blockIdx.x;
  size_t R0 = (size_t)b*SS + w*16;
  // ---- cooperative coalesced weight staging ----
  if (tid < 256){                       // w1: 32 rows x 8 chunks
    int row = tid >> 3, ch = tid & 7;
    const float* g = fW1 + row*64 + ch*8;
    h8 f;
#pragma unroll
    for (int j=0;j<8;++j) f[j] = (_Float16)(g[j]*S_TANH);
    *(h8*)&w1l[((((row>>4)*2 + (ch>>2))*64) + (row&15) + 16*(ch&3))*8] = f;
  } else {                              // w2: 64 rows x 4 chunks
    int idx = tid - 256;
    int row = idx >> 2, ch = idx & 3;
    const float* g = fW2 + row*32 + ch*8;
    h8 f;
#pragma unroll
    for (int j=0;j<8;++j) f[j] = (_Float16)(g[j]);
    *(h8*)&w2l[(((row>>4)*64) + (row&15) + 16*ch)*8] = f;
  }
  for (int idx = tid; idx < 64*12; idx += 512){   // w3: 64 x 12
    int row = idx / 12, ch = idx % 12;
    const float* g = cW1 + row*96 + ch*8;
    h8 f;
#pragma unroll
    for (int j=0;j<8;++j) f[j] = (_Float16)(g[j]*S_TANH);
    *(h8*)&w3l[((((row>>4)*3 + (ch>>2))*64) + (row&15) + 16*(ch&3))*8] = f;
  }
  {                                     // w4: 64 x 8 = 512
    int row = tid >> 3, ch = tid & 7;
    const float* g = cW2 + row*64 + ch*8;
    h8 f;
#pragma unroll
    for (int j=0;j<8;++j) f[j] = (_Float16)(g[j]);
    *(h8*)&w4l[((((row>>4)*2 + (ch>>2))*64) + (row&15) + 16*(ch&3))*8] = f;
  }
  // stage x rows (f16): lane covers row lm, feats lq*16..+15
  {
    const float* xr = x + (R0+lm)*64 + lq*16;
    float4 x0 = *(const float4*)xr;
    float4 x1 = *(const float4*)(xr+4);
    float4 x2 = *(const float4*)(xr+8);
    float4 x3 = *(const float4*)(xr+12);
    h8 hx0 = {(_Float16)x0.x,(_Float16)x0.y,(_Float16)x0.z,(_Float16)x0.w,
              (_Float16)x1.x,(_Float16)x1.y,(_Float16)x1.z,(_Float16)x1.w};
    h8 hx1 = {(_Float16)x2.x,(_Float16)x2.y,(_Float16)x2.z,(_Float16)x2.w,
              (_Float16)x3.x,(_Float16)x3.y,(_Float16)x3.z,(_Float16)x3.w};
    *(h8*)&xt[T64(lm, lq*16)] = hx0;
    *(h8*)&xt[T64(lm, lq*16+8)] = hx1;
  }
  // proc part of cmb (k=64..95)
  {
    float4 p0 = *(const float4*)&proc[b*32 + lq*8];
    float4 p1 = *(const float4*)&proc[b*32 + lq*8 + 4];
    h8 ph = {(_Float16)p0.x,(_Float16)p0.y,(_Float16)p0.z,(_Float16)p0.w,
             (_Float16)p1.x,(_Float16)p1.y,(_Float16)p1.z,(_Float16)p1.w};
    *(h8*)&tB[TADDR(lm, 64+lq*8)] = ph;
  }
  __syncthreads();
  // ---- L1 ----
  {
    h8 bx0 = *(const h8*)&xt[T64(lm, lq*8)];
    h8 bx1 = *(const h8*)&xt[T64(lm, 32+lq*8)];
#pragma unroll
    for (int mt=0;mt<2;++mt){
      h8 f0 = *(const h8*)&w1l[((mt*2+0)*64 + l)*8];
      h8 f1 = *(const h8*)&w1l[((mt*2+1)*64 + l)*8];
      float4 t = *(const float4*)&fb1[mt*16 + lq*4];
      f4v bv = {t.x*S_TANH, t.y*S_TANH, t.z*S_TANH, t.w*S_TANH};
      f4v a = __builtin_amdgcn_mfma_f32_16x16x32_f16(f0, bx0, bv,0,0,0);
      a = __builtin_amdgcn_mfma_f32_16x16x32_f16(f1, bx1, a,0,0,0);
      h4 tv = {(_Float16)tanh2(a[0]),(_Float16)tanh2(a[1]),
               (_Float16)tanh2(a[2]),(_Float16)tanh2(a[3])};
      *(h4*)&tA[T64(lm, mt*16+lq*4)] = tv;
    }
  }
  // ---- L2 ----
  {
    h8 bt = *(const h8*)&tA[T64(lm, lq*8)];
#pragma unroll
    for (int mt=0;mt<4;++mt){
      h8 f = *(const h8*)&w2l[(mt*64 + l)*8];
      float4 t = *(const float4*)&fb2[mt*16 + lq*4];
      f4v bv = {t.x, t.y, t.z, t.w};
      f4v a = __builtin_amdgcn_mfma_f32_16x16x32_f16(f, bt, bv,0,0,0);
      h4 fv = {(_Float16)a[0],(_Float16)a[1],(_Float16)a[2],(_Float16)a[3]};
      *(h4*)&tB[TADDR(lm, mt*16+lq*4)] = fv;
    }
  }
  // ---- L3 ----
  {
    h8 bc0 = *(const h8*)&tB[TADDR(lm, lq*8)];
    h8 bc1 = *(const h8*)&tB[TADDR(lm, 32+lq*8)];
    h8 bc2 = *(const h8*)&tB[TADDR(lm, 64+lq*8)];
#pragma unroll
    for (int mt=0;mt<4;++mt){
      h8 f0 = *(const h8*)&w3l[((mt*3+0)*64 + l)*8];
      h8 f1 = *(const h8*)&w3l[((mt*3+1)*64 + l)*8];
      h8 f2 = *(const h8*)&w3l[((mt*3+2)*64 + l)*8];
      float4 t = *(const float4*)&cb1[mt*16 + lq*4];
      f4v bv = {t.x*S_TANH, t.y*S_TANH, t.z*S_TANH, t.w*S_TANH};
      f4v z = {0.f,0.f,0.f,0.f};
      f4v a = __builtin_amdgcn_mfma_f32_16x16x32_f16(f0, bc0, bv,0,0,0);
      f4v c = __builtin_amdgcn_mfma_f32_16x16x32_f16(f1, bc1, z,0,0,0);
      a = __builtin_amdgcn_mfma_f32_16x16x32_f16(f2, bc2, a,0,0,0);
      a = a + c;
      h4 hv = {(_Float16)tanh2(a[0]),(_Float16)tanh2(a[1]),
               (_Float16)tanh2(a[2]),(_Float16)tanh2(a[3])};
      *(h4*)&tA[T64(lm, mt*16+lq*4)] = hv;
    }
  }
  // ---- L4 + softmax + outputs ----
  f4v a4[4];
  {
    h8 bh0 = *(const h8*)&tA[T64(lm, lq*8)];
    h8 bh1 = *(const h8*)&tA[T64(lm, 32+lq*8)];
#pragma unroll
    for (int mt=0;mt<4;++mt){
      h8 f0 = *(const h8*)&w4l[((mt*2+0)*64 + l)*8];
      h8 f1 = *(const h8*)&w4l[((mt*2+1)*64 + l)*8];
      float4 t = *(const float4*)&cb2[mt*16 + lq*4];
      f4v bv = {t.x, t.y, t.z, t.w};
      f4v a = __builtin_amdgcn_mfma_f32_16x16x32_f16(f0, bh0, bv,0,0,0);
      a4[mt] = __builtin_amdgcn_mfma_f32_16x16x32_f16(f1, bh1, a,0,0,0);
    }
  }
  float mx = a4[0][0];
#pragma unroll
  for (int mt=0;mt<4;++mt)
#pragma unroll
    for (int r=0;r<4;++r) mx = fmaxf(mx, a4[mt][r]);
  mx = fmaxf(mx, __shfl_xor(mx,16,64));
  mx = fmaxf(mx, __shfl_xor(mx,32,64));
  f4v e4[4];
  float s = 0.f;
#pragma unroll
  for (int mt=0;mt<4;++mt)
#pragma unroll
    for (int r=0;r<4;++r){
      float e = fexp2((a4[mt][r]-mx)*LOG2E);
      e4[mt][r] = e; s += e;
    }
  s += __shfl_xor(s,16,64);
  s += __shfl_xor(s,32,64);
  float rs = frcp(s);
#pragma unroll
  for (int mt=0;mt<4;++mt){
    h4 xh = *(const h4*)&xt[T64(lm, mt*16+lq*4)];
    float4 fwv;
    fwv.x = e4[mt][0]*rs; fwv.y = e4[mt][1]*rs;
    fwv.z = e4[mt][2]*rs; fwv.w = e4[mt][3]*rs;
    h4 wh = {(_Float16)((float)xh[0]*fwv.x), (_Float16)((float)xh[1]*fwv.y),
             (_Float16)((float)xh[2]*fwv.z), (_Float16)((float)xh[3]*fwv.w)};
    size_t off = (R0+lm)*64 + mt*16 + lq*4;
    *(float4*)&fw_out[off] = fwv;
    *(h4*)&wxh[off] = wh;
  }
}

// ================= MFMA encoder LSTM (swapped operands) =================
// ench: f16 copy of enc, row-padded to 112 (units 100..111 zeroed).
__global__ __launch_bounds__(448) void k_enc_mfma(const _Float16* __restrict__ wxh,
    const float* __restrict__ Wih, const float* __restrict__ Whh,
    const float* __restrict__ bih, const float* __restrict__ bhh,
    _Float16* __restrict__ ench){
  __shared__ __align__(16) _Float16 hbuf[2][16*128];
  __shared__ __align__(16) _Float16 xst[2][16*64];
  int tid = threadIdx.x;
  int w = tid >> 6, l = tid & 63;
  int lm = l & 15, lq = l >> 4;
  int b0 = blockIdx.x * 16;
  int au = w*16 + lm;
  bool avalid = au < 100;
  int u0 = w*16 + lq*4;
  bool uvalid = (u0 + 3) < 100;
  const float gsc[4] = {S_SIG, S_SIG, S_TANH, S_SIG};   // gate order i,f,g,o
  h8 wfr[4][6];
#pragma unroll
  for (int tt=0; tt<4; ++tt){
    int row = tt*100 + au;
#pragma unroll
    for (int cc=0; cc<6; ++cc){
      h8 f;
#pragma unroll
      for (int j=0;j<8;++j){
        int kg = cc*32 + lq*8 + j;
        float v = 0.f;
        if (avalid){
          if (kg < 64) v = Wih[(size_t)row*64 + kg];
          else { int kh = kg - 64; if (kh < 100) v = Whh[(size_t)row*100 + kh]; }
        }
        f[j] = (_Float16)(v*gsc[tt]);
      }
      wfr[tt][cc] = f;
    }
  }
  f4v biasv[4];
#pragma unroll
  for (int tt=0; tt<4; ++tt){
    if (uvalid){
      float4 bi = *(const float4*)&bih[tt*100 + u0];
      float4 bh = *(const float4*)&bhh[tt*100 + u0];
      float s = gsc[tt];
      f4v bv2 = {(bi.x+bh.x)*s, (bi.y+bh.y)*s, (bi.z+bh.z)*s, (bi.w+bh.w)*s};
      biasv[tt] = bv2;
    } else { f4v z = {0,0,0,0}; biasv[tt] = z; }
  }
  for (int i = tid; i < 2*16*128; i += 448) hbuf[0][i] = (_Float16)0.f;
  int sm = tid >> 4, skq = tid & 15;
  bool doPref = (tid < 256);
  int xwaddr = sm*64 + (((skq>>1) ^ (sm&7))<<3) + (skq&1)*4;
  h4 rA, rB;
  if (doPref){
    *(h4*)&xst[0][xwaddr] = *(const h4*)(wxh + ((size_t)(b0+sm)*SS + 0)*FF + skq*4);
    rA = *(const h4*)(wxh + ((size_t)(b0+sm)*SS + 1)*FF + skq*4);   // x(1)
  }
  float cst[4] = {0.f,0.f,0.f,0.f};   // pre-scaled cell state (c * 2/ln2)
  int hwaddr = lm*128 + (((2*w + (lq>>1)) ^ (lm&7))<<3) + (lq&1)*4;
  __syncthreads();

#define ENC_STEP(T, CUR, RCONS, RISSUE)                                          \
  {                                                                              \
    const int cur = (CUR), nxt = (CUR)^1;                                        \
    if (doPref && (T) < SS-2)                                                    \
      RISSUE = *(const h4*)(wxh + ((size_t)(b0+sm)*SS + ((T)+2))*FF + skq*4);    \
    h8 bact[6];                                                                  \
    _Pragma("unroll")                                                            \
    for (int cc=0; cc<2; ++cc)                                                   \
      bact[cc] = *(const h8*)&xst[cur][lm*64 + (((cc*4+lq) ^ (lm&7))<<3)];       \
    _Pragma("unroll")                                                            \
    for (int cc=0; cc<4; ++cc)                                                   \
      bact[2+cc] = *(const h8*)&hbuf[cur][lm*128 + (((cc*4+lq) ^ (lm&7))<<3)];   \
    f4v acc[4];                                                                  \
    __builtin_amdgcn_s_setprio(1);                                               \
    _Pragma("unroll")                                                            \
    for (int tt=0; tt<4; ++tt){                                                  \
      f4v a1 = biasv[tt];                                                        \
      f4v a2 = {0.f,0.f,0.f,0.f};                                                \
      a1 = __builtin_amdgcn_mfma_f32_16x16x32_f16(wfr[tt][0], bact[0], a1, 0,0,0); \
      a2 = __builtin_amdgcn_mfma_f32_16x16x32_f16(wfr[tt][1], bact[1], a2, 0,0,0); \
      a1 = __builtin_amdgcn_mfma_f32_16x16x32_f16(wfr[tt][2], bact[2], a1, 0,0,0); \
      a2 = __builtin_amdgcn_mfma_f32_16x16x32_f16(wfr[tt][3], bact[3], a2, 0,0,0); \
      a1 = __builtin_amdgcn_mfma_f32_16x16x32_f16(wfr[tt][4], bact[4], a1, 0,0,0); \
      a2 = __builtin_amdgcn_mfma_f32_16x16x32_f16(wfr[tt][5], bact[5], a2, 0,0,0); \
      acc[tt] = a1 + a2;                                                         \
    }                                                                            \
    __builtin_amdgcn_s_setprio(0);                                               \
    float hn[4];                                                                 \
    _Pragma("unroll")                                                            \
    for (int r=0;r<4;++r){                                                       \
      float Ei = fexp2(acc[0][r]), Ef = fexp2(acc[1][r]);                        \
      float Eg = fexp2(acc[2][r]), Eo = fexp2(acc[3][r]);                        \
      float cn2 = frcp(1.f+Ef)*cst[r] + sigtanhT(Ei, Eg);                        \
      float Ec = fexp2(cn2);                                                     \
      hn[r] = sigtanh(Eo, Ec);                                                   \
      cst[r] = cn2;                                                              \
    }                                                                            \
    if (uvalid){                                                                 \
      h4 hp = {(_Float16)hn[0],(_Float16)hn[1],(_Float16)hn[2],(_Float16)hn[3]}; \
      *(h4*)&hbuf[nxt][hwaddr] = hp;                                             \
      *(h4*)&ench[((size_t)(b0+lm)*SS + (T))*112 + u0] = hp;                     \
    } else {                                                                     \
      h4 z = {(_Float16)0.f,(_Float16)0.f,(_Float16)0.f,(_Float16)0.f};          \
      *(h4*)&ench[((size_t)(b0+lm)*SS + (T))*112 + u0] = z;                      \
    }                                                                            \
    if (doPref && (T) < SS-1){                                                   \
      *(h4*)&xst[nxt][xwaddr] = RCONS;                                           \
    }                                                                            \
    LDS_BARRIER();                                                               \
  }

  for (int t = 0; t < SS; t += 2){
    ENC_STEP(t,   0, rA, rB)
    ENC_STEP(t+1, 1, rB, rA)
  }
#undef ENC_STEP
}

// ====== ts GEMM + attn2 (one block per batch) ======
// R13: ends at bott (written to global); the dh0/dc0/decpre projections moved
// into k_dec's prologue (64 blocks instead of 1024 -> kills the scattered
// 600x32 GEMV re-reads and the 4.9MB intermediate round-trips).
__global__ __launch_bounds__(256) void k_tsattn2(const _Float16* __restrict__ ench,
    const float* __restrict__ aW1, const float* __restrict__ ab1,
    const float* __restrict__ aW2, const float* __restrict__ ab2,
    const float* __restrict__ bW, const float* __restrict__ bb_,
    float* __restrict__ tw_out, float* __restrict__ bott_out){
  __shared__ __align__(16) _Float16 awl[64*128];   // 16KB frag-ordered
  __shared__ float tsb[SS];
  __shared__ float ctxb[HH];
  __shared__ float ctx2[200];
  __shared__ float red[8];
  int tid = threadIdx.x, wv = tid>>6, lane = tid&63, lm = lane&15, lq = lane>>4;
  int b = blockIdx.x;
  for (int idx = tid; idx < 64*16; idx += 256){
    int row = idx >> 4, ch = idx & 15;
    h8 f;
#pragma unroll
    for (int j=0;j<8;++j){
      int k = ch*8 + j;
      f[j] = (_Float16)((k<100) ? aW1[row*100+k]*S_TANH : 0.f);
    }
    *(h8*)&awl[((((row>>4)*4 + (ch>>2))*64) + (row&15) + 16*(ch&3))*8] = f;
  }
  __syncthreads();
  {
    float ab1v[4], aw2v[4];
#pragma unroll
    for (int nt=0; nt<4; ++nt){ ab1v[nt] = ab1[nt*16+lm]*S_TANH; aw2v[nt] = aW2[nt*16+lm]; }
    float ab2v = ab2[0];
#pragma unroll
    for (int i=0;i<2;++i){
      int M0 = b*SS + wv*32 + i*16;
      const _Float16* rowp = ench + (size_t)(M0+lm)*112;
      h8 afr[4];
#pragma unroll
      for (int cc=0; cc<3; ++cc)
        afr[cc] = *(const h8*)(rowp + cc*32 + lq*8);
      if (lq < 2) afr[3] = *(const h8*)(rowp + 96 + lq*8);
      else { h8 z={0,0,0,0,0,0,0,0}; afr[3]=z; }
      f4v acc[4];
#pragma unroll
      for (int nt=0; nt<4; ++nt){
        f4v a = {ab1v[nt],ab1v[nt],ab1v[nt],ab1v[nt]};
#pragma unroll
        for (int cc=0; cc<4; ++cc){
          h8 bf = *(const h8*)&awl[((nt*4+cc)*64 + lane)*8];
          a = __builtin_amdgcn_mfma_f32_16x16x32_f16(afr[cc], bf, a, 0,0,0);
        }
        acc[nt]=a;
      }
      float p[4];
#pragma unroll
      for (int r=0;r<4;++r){
        p[r] = aw2v[0]*tanh2(acc[0][r]) + aw2v[1]*tanh2(acc[1][r])
             + aw2v[2]*tanh2(acc[2][r]) + aw2v[3]*tanh2(acc[3][r]);
#pragma unroll
        for (int m=1;m<16;m<<=1) p[r] += __shfl_xor(p[r], m, 64);
      }
      if (lm==0){
        float4 st; st.x=p[0]+ab2v; st.y=p[1]+ab2v; st.z=p[2]+ab2v; st.w=p[3]+ab2v;
        *(float4*)&tsb[wv*32 + i*16 + lq*4] = st;
      }
    }
  }
  __syncthreads();
  const _Float16* encb = ench + (size_t)b*SS*112;
  float tv = (tid < SS) ? tsb[tid] : -1e30f;
  float m = wmax(tv);
  if (lane==0) red[wv]=m;
  __syncthreads();
  m = fmaxf(fmaxf(red[0],red[1]), fmaxf(red[2],red[3]));
  float e = (tid < SS) ? __expf(tv - m) : 0.f;
  float sm = wsum(e);
  if (lane==0) red[4+wv]=sm;
  __syncthreads();
  float denom = red[4]+red[5]+red[6]+red[7];
  float rden = frcp(denom);
  if (tid < SS){
    float twv = e*rden;
    tw_out[(size_t)b*SS + tid] = twv;
    tsb[tid] = twv;
  }
  __syncthreads();
  if (tid < 200){
    int u = (tid < 100) ? tid : (tid - 100);
    int sb = (tid < 100) ? 0 : 64;
    const _Float16* ep = encb + (size_t)sb*112 + u;
    const float* tp = tsb + sb;
    float a = 0.f;
#pragma unroll 4
    for (int s=0;s<64;++s) a += tp[s]*(float)ep[s*112];
    ctx2[tid] = a;
  }
  __syncthreads();
  if (tid < HH) ctxb[tid] = ctx2[tid] + ctx2[tid+100];
  __syncthreads();
  if (tid < 32){
    float a = bb_[tid];
    const float* wr = bW + tid*HH;
    for (int k=0;k<HH;++k) a += wr[k]*ctxb[k];
    bott_out[(size_t)b*32 + tid] = a;
  }
}

// ================= MFMA decoder LSTM (swapped operands) =================
// R13 prologue: computes dh0/dc0/decpre IN-BLOCK from bott via 38 MFMA tiles
// (W_all = [h0W;c0W;dWih] staged coalesced f16, 64 blocks only), results
// redistributed through a proj[16][612] f32 LDS tile (stride 612: 16B-aligned
// float4s, 2-way banks). Deletes the old per-batch scattered GEMVs (1024x)
// and the decpre/dh0/dc0 global round-trips.
__global__ __launch_bounds__(448) void k_dec_mfma(const float* __restrict__ bottg,
    const float* __restrict__ Whh,
    const float* __restrict__ h0W, const float* __restrict__ h0b,
    const float* __restrict__ c0W, const float* __restrict__ c0b,
    const float* __restrict__ dWih, const float* __restrict__ dbih, const float* __restrict__ dbhh,
    _Float16* __restrict__ dech){
  __shared__ __align__(16) _Float16 hbuf[2][16*128];     // 8KB
  __shared__ __align__(16) _Float16 walls[38*64*8];      // 38KB frag-ordered W_all
  __shared__ __align__(16) float proj[16*612];           // 39.2KB [batch][unit]
  __shared__ __align__(16) float biasl[608];             // 2.4KB
  int tid = threadIdx.x;
  int w = tid >> 6, l = tid & 63;
  int lm = l & 15, lq = l >> 4;
  int b0 = blockIdx.x * 16;
  int au = w*16 + lm;
  bool avalid = au < 100;
  int u0 = w*16 + lq*4;
  bool uvalid = (u0 + 3) < 100;
  const float gsc[4] = {S_SIG, S_SIG, S_TANH, S_SIG};
  h8 wfr[4][4];
#pragma unroll
  for (int tt = 0; tt < 4; ++tt){
    int row = tt*100 + au;
#pragma unroll
    for (int cc = 0; cc < 4; ++cc){
      h8 f;
#pragma unroll
      for (int j = 0; j < 8; ++j){
        int kh = cc*32 + lq*8 + j;
        float v = (avalid && kh < 100) ? Whh[(size_t)row*100 + kh] : 0.f;
        f[j] = (_Float16)(v*gsc[tt]);
      }
      wfr[tt][cc] = f;
    }
  }
  // ---- prologue staging: biases + W_all (600 rows x K=32, rows 600-607 zero) ----
  for (int idx = tid; idx < 608; idx += 448)
    biasl[idx] = (idx<100) ? h0b[idx] : (idx<200) ? c0b[idx-100]
               : (idx<600) ? (dbih[idx-200]+dbhh[idx-200]) : 0.f;
  for (int idx = tid; idx < 608*4; idx += 448){
    int row = idx >> 2, q = idx & 3;     // q: 8-elem chunk (lq)
    h8 f;
    if (row < 600){
      const float* src = (row<100) ? (h0W + row*32) : (row<200) ? (c0W + (row-100)*32)
                                   : (dWih + (row-200)*32);
      float4 a0 = *(const float4*)(src + q*8);
      float4 a1 = *(const float4*)(src + q*8 + 4);
      h8 t = {(_Float16)a0.x,(_Float16)a0.y,(_Float16)a0.z,(_Float16)a0.w,
              (_Float16)a1.x,(_Float16)a1.y,(_Float16)a1.z,(_Float16)a1.w};
      f = t;
    } else { h8 z = {0,0,0,0,0,0,0,0}; f = z; }
    *(h8*)&walls[(((row>>4)*64) + (row&15) + 16*q)*8] = f;
  }
  // A-frag: bott rows (batches b0+lm), k = lq*8+j
  h8 bfrag;
  {
    const float* bp = bottg + (size_t)(b0+lm)*32 + lq*8;
    float4 a0 = *(const float4*)bp;
    float4 a1 = *(const float4*)(bp+4);
    h8 t = {(_Float16)a0.x,(_Float16)a0.y,(_Float16)a0.z,(_Float16)a0.w,
            (_Float16)a1.x,(_Float16)a1.y,(_Float16)a1.z,(_Float16)a1.w};
    bfrag = t;
  }
  for (int i = tid; i < 16*128; i += 448) hbuf[1][i] = (_Float16)0.f;
  __syncthreads();
  // ---- prologue MFMA: proj[batch][unit] = W_all @ bott + bias ----
  for (int nt = w; nt < 38; nt += 7){
    float bv = biasl[nt*16 + lm];
    f4v a = {bv, bv, bv, bv};
    h8 bf = *(const h8*)&walls[(nt*64 + l)*8];
    a = __builtin_amdgcn_mfma_f32_16x16x32_f16(bfrag, bf, a, 0,0,0);
#pragma unroll
    for (int r=0;r<4;++r)
      proj[(lq*4+r)*612 + nt*16 + lm] = a[r];
  }
  __syncthreads();
  // ---- distribute: pre (decpre), cst (dc0), hbuf[0] (dh0) ----
  f4v pre[4];
  float cst[4] = {0.f,0.f,0.f,0.f};
  if (uvalid){
#pragma unroll
    for (int tt = 0; tt < 4; ++tt){
      float4 p = *(const float4*)&proj[lm*612 + 200 + tt*100 + u0];
      float s = gsc[tt];
      f4v pv = {p.x*s, p.y*s, p.z*s, p.w*s};
      pre[tt] = pv;
    }
    float4 c4 = *(const float4*)&proj[lm*612 + 100 + u0];
    cst[0]=c4.x*S_TANH; cst[1]=c4.y*S_TANH; cst[2]=c4.z*S_TANH; cst[3]=c4.w*S_TANH;
  } else {
    f4v z = {0,0,0,0};
#pragma unroll
    for (int tt = 0; tt < 4; ++tt) pre[tt] = z;
  }
  for (int idx = tid; idx < 16*128; idx += 448){
    int m = idx >> 7, u2 = idx & 127;
    float v = (u2 < 100) ? proj[m*612 + u2] : 0.f;
    hbuf[0][m*128 + (((u2>>3) ^ (m&7))<<3) + (u2&7)] = (_Float16)v;
  }
  int hwaddr = lm*128 + (((2*w + (lq>>1)) ^ (lm&7))<<3) + (lq&1)*4;
  __syncthreads();

#define DEC_STEP(T, CUR)                                                         \
  {                                                                              \
    const int cur = (CUR), nxt = (CUR)^1;                                        \
    h8 bact[4];                                                                  \
    _Pragma("unroll")                                                            \
    for (int cc = 0; cc < 4; ++cc)                                               \
      bact[cc] = *(const h8*)&hbuf[cur][lm*128 + (((cc*4+lq) ^ (lm&7))<<3)];     \
    f4v acc[4];                                                                  \
    __builtin_amdgcn_s_setprio(1);                                               \
    _Pragma("unroll")                                                            \
    for (int tt = 0; tt < 4; ++tt){                                              \
      f4v a1 = pre[tt];                                                          \
      f4v a2 = {0.f,0.f,0.f,0.f};                                                \
      a1 = __builtin_amdgcn_mfma_f32_16x16x32_f16(wfr[tt][0], bact[0], a1, 0,0,0); \
      a2 = __builtin_amdgcn_mfma_f32_16x16x32_f16(wfr[tt][1], bact[1], a2, 0,0,0); \
      a1 = __builtin_amdgcn_mfma_f32_16x16x32_f16(wfr[tt][2], bact[2], a1, 0,0,0); \
      a2 = __builtin_amdgcn_mfma_f32_16x16x32_f16(wfr[tt][3], bact[3], a2, 0,0,0); \
      acc[tt] = a1 + a2;                                                         \
    }                                                                            \
    __builtin_amdgcn_s_setprio(0);                                               \
    float hn[4];                                                                 \
    _Pragma("unroll")                                                            \
    for (int r=0;r<4;++r){                                                       \
      float Ei = fexp2(acc[0][r]), Ef = fexp2(acc[1][r]);                        \
      float Eg = fexp2(acc[2][r]), Eo = fexp2(acc[3][r]);                        \
      float cn2 = frcp(1.f+Ef)*cst[r] + sigtanhT(Ei, Eg);                        \
      float Ec = fexp2(cn2);                                                     \
      hn[r] = sigtanh(Eo, Ec);                                                   \
      cst[r] = cn2;                                                              \
    }                                                                            \
    if (uvalid){                                                                 \
      h4 hp = {(_Float16)hn[0],(_Float16)hn[1],(_Float16)hn[2],(_Float16)hn[3]}; \
      *(h4*)&hbuf[nxt][hwaddr] = hp;                                             \
      *(h4*)&dech[((size_t)(b0+lm)*SS + (T))*112 + u0] = hp;                     \
    } else {                                                                     \
      h4 z = {(_Float16)0.f,(_Float16)0.f,(_Float16)0.f,(_Float16)0.f};          \
      *(h4*)&dech[((size_t)(b0+lm)*SS + (T))*112 + u0] = z;                      \
    }                                                                            \
    LDS_BARRIER();                                                               \
  }

  for (int t = 0; t < SS; t += 2){
    DEC_STEP(t,   0)
    DEC_STEP(t+1, 1)
  }
#undef DEC_STEP
}

// ------------- out = dech @ oW^T + ob, MFMA -------------
__global__ __launch_bounds__(256) void k_out(const _Float16* __restrict__ dech,
    const float* __restrict__ oW, const float* __restrict__ ob, float* __restrict__ out0){
  __shared__ __align__(16) _Float16 owl[64*128];   // 16KB frag-ordered
  int tid = threadIdx.x, wv = tid>>6, l = tid&63, lm = l&15, lq = l>>4;
  for (int idx = tid; idx < 64*16; idx += 256){
    int row = idx >> 4, ch = idx & 15;
    h8 f;
#pragma unroll
    for (int j=0;j<8;++j){
      int k = ch*8 + j;
      f[j] = (_Float16)((k<100) ? oW[row*100+k] : 0.f);
    }
    *(h8*)&owl[((((row>>4)*4 + (ch>>2))*64) + (row&15) + 16*(ch&3))*8] = f;
  }
  __syncthreads();
  float obv[4];
#pragma unroll
  for (int nt=0; nt<4; ++nt) obv[nt] = ob[nt*16+lm];
  int tile0 = (blockIdx.x*4 + wv)*4;
#pragma unroll
  for (int i=0;i<4;++i){
    int M0 = (tile0+i)*16;
    const _Float16* rowp = dech + (size_t)(M0+lm)*112;
    h8 afr[4];
#pragma unroll
    for (int cc=0; cc<3; ++cc)
      afr[cc] = *(const h8*)(rowp + cc*32 + lq*8);
    if (lq < 2) afr[3] = *(const h8*)(rowp + 96 + lq*8);
    else { h8 z={0,0,0,0,0,0,0,0}; afr[3]=z; }
#pragma unroll
    for (int nt=0; nt<4; ++nt){
      f4v a = {obv[nt],obv[nt],obv[nt],obv[nt]};
#pragma unroll
      for (int cc=0; cc<4; ++cc){
        h8 bf = *(const h8*)&owl[((nt*4+cc)*64 + l)*8];
        a = __builtin_amdgcn_mfma_f32_16x16x32_f16(afr[cc], bf, a, 0,0,0);
      }
#pragma unroll
      for (int r=0;r<4;++r)
        out0[(size_t)(M0 + lq*4 + r)*64 + nt*16 + lm] = a[r];
    }
  }
}

extern "C" void kernel_launch(void* const* d_in, const int* in_sizes, int n_in,
                              void* d_out, int out_size, void* d_ws, size_t ws_size,
                              hipStream_t stream) {
  const float* x    = (const float*)d_in[0];
  const float* c1w  = (const float*)d_in[1];
  const float* c1b  = (const float*)d_in[2];
  const float* c2w  = (const float*)d_in[3];
  const float* c2b  = (const float*)d_in[4];
  const float* fW1  = (const float*)d_in[5];
  const float* fb1  = (const float*)d_in[6];
  const float* fW2  = (const float*)d_in[7];
  const float* fb2  = (const float*)d_in[8];
  const float* cW1  = (const float*)d_in[9];
  const float* cb1  = (const float*)d_in[10];
  const float* cW2  = (const float*)d_in[11];
  const float* cb2  = (const float*)d_in[12];
  const float* eWih = (const float*)d_in[13];
  const float* eWhh = (const float*)d_in[14];
  const float* ebih = (const float*)d_in[15];
  const float* ebhh = (const float*)d_in[16];
  const float* aW1  = (const float*)d_in[17];
  const float* ab1  = (const float*)d_in[18];
  const float* aW2  = (const float*)d_in[19];
  const float* ab2  = (const float*)d_in[20];
  const float* bW   = (const float*)d_in[21];
  const float* bb   = (const float*)d_in[22];
  const float* h0W  = (const float*)d_in[23];
  const float* h0b  = (const float*)d_in[24];
  const float* c0W  = (const float*)d_in[25];
  const float* c0b  = (const float*)d_in[26];
  const float* dWih = (const float*)d_in[27];
  const float* dWhh = (const float*)d_in[28];
  const float* dbih = (const float*)d_in[29];
  const float* dbhh = (const float*)d_in[30];
  const float* oW   = (const float*)d_in[31];
  const float* ob   = (const float*)d_in[32];

  float* out0   = (float*)d_out;
  float* out_tw = out0 + (size_t)BB*SS*FF;
  float* out_fw = out_tw + (size_t)BB*SS;

  char* ws = (char*)d_ws;
  float*  proc    = (float*) (ws + 50331648);    // 0.13 MB
  _Float16* wxh   = (_Float16*)(ws + 84017152);  // 16.78 MB (f16, [b*S+s][64])
  float*  bott_ws = (float*) (ws + 170000384);   // 0.13 MB [b][32]
  _Float16* dech  = (_Float16*)(ws + 172457984); // 29.36 MB (f16, [row][112])
  _Float16* ench  = (_Float16*)(ws + 50462720);  // 29.36 MB

  k_conv<<<BB, 512, 0, stream>>>(x, c1w, c1b, c2w, c2b, proc);
  k_feat<<<BB, 512, 0, stream>>>(x, proc, fW1, fb1, fW2, fb2,
                                 cW1, cb1, cW2, cb2, out_fw, wxh);
  k_enc_mfma<<<64, 448, 0, stream>>>(wxh, eWih, eWhh, ebih, ebhh, ench);
  k_tsattn2<<<BB, 256, 0, stream>>>(ench, aW1, ab1, aW2, ab2, bW, bb,
                                    out_tw, bott_ws);
  k_dec_mfma<<<64, 448, 0, stream>>>(bott_ws, dWhh, h0W, h0b, c0W, c0b,
                                     dWih, dbih, dbhh, dech);
  k_out<<<512, 256, 0, stream>>>(dech, oW, ob, out0);
}